// Round 8
// baseline (667.560 us; speedup 1.0000x reference)
//
#include <hip/hip_runtime.h>
#include <hip/hip_bf16.h>
#include <math.h>

#define Tn 1024
#define Hn 2048
#define En 64
#define Kn 6
#define In 1024
#define Gn 8
#define TGn 3
#define Cn 256
#define Sn 2048
#define RSF 2.5

typedef __bf16 bf16x8 __attribute__((ext_vector_type(8)));
typedef __bf16 bf16x4 __attribute__((ext_vector_type(4)));
typedef float f32x4 __attribute__((ext_vector_type(4)));

// swizzled byte offset within a [rows][64 bf16] (128B-row) LDS tile.
__device__ __forceinline__ int swz(int row, int kbyte) {
  return row * 128 + (kbyte ^ ((((row >> 2) ^ row) & 7) << 4));
}

// one barrier per K-step: make LDS writes visible, never drain vmcnt.
#define BAR()                                                  \
  do {                                                         \
    asm volatile("s_waitcnt lgkmcnt(0)" ::: "memory");         \
    __builtin_amdgcn_sched_barrier(0);                         \
    __builtin_amdgcn_s_barrier();                              \
    __builtin_amdgcn_sched_barrier(0);                         \
  } while (0)

// ---------------- x -> bf16 pre-pass ----------------
__global__ void xcvt_kernel(const float* __restrict__ x, __bf16* __restrict__ xbf) {
  int i = (blockIdx.x * 256 + threadIdx.x) * 8;
  float4 v0 = *(const float4*)(x + i);
  float4 v1 = *(const float4*)(x + i + 4);
  bf16x8 h;
  h[0] = (__bf16)v0.x; h[1] = (__bf16)v0.y; h[2] = (__bf16)v0.z; h[3] = (__bf16)v0.w;
  h[4] = (__bf16)v1.x; h[5] = (__bf16)v1.y; h[6] = (__bf16)v1.z; h[7] = (__bf16)v1.w;
  *(bf16x8*)(xbf + i) = h;
}

// ---------------- router: sigmoid(x @ gate_w^T) in fp64 + grouped top-k ----------------
__global__ void router_kernel(const float* __restrict__ x, const float* __restrict__ gw,
                              const float* __restrict__ gb, int* __restrict__ ids,
                              float* __restrict__ tw) {
  __shared__ float xs[Hn];
  __shared__ double sds[En];
  __shared__ double gs[Gn];
  int t = blockIdx.x;
  for (int i = threadIdx.x * 4; i < Hn; i += 64 * 4)
    *(float4*)(xs + i) = *(const float4*)(x + (size_t)t * Hn + i);
  __syncthreads();
  int e = threadIdx.x;
  const float* w = gw + (size_t)e * Hn;
  double a0 = 0.0, a1 = 0.0, a2 = 0.0, a3 = 0.0;
  for (int i = 0; i < Hn; i += 4) {
    float4 b = *(const float4*)(w + i);
    a0 += (double)xs[i] * b.x;
    a1 += (double)xs[i + 1] * b.y;
    a2 += (double)xs[i + 2] * b.z;
    a3 += (double)xs[i + 3] * b.w;
  }
  double acc = (a0 + a1) + (a2 + a3);
  sds[e] = 1.0 / (1.0 + exp(-acc));
  __syncthreads();
  if (e < Gn) {
    double m1 = -1e300, m2 = -1e300;
    for (int j = 0; j < 8; ++j) {
      double v = sds[e * 8 + j] + (double)gb[e * 8 + j];
      if (v > m1) { m2 = m1; m1 = v; } else if (v > m2) m2 = v;
    }
    gs[e] = m1 + m2;
  }
  __syncthreads();
  if (e == 0) {
    unsigned gsel = 0;
    for (int it = 0; it < TGn; ++it) {
      double best = -1e300; int bi = 0;
      for (int g = 0; g < Gn; ++g)
        if (!((gsel >> g) & 1) && gs[g] > best) { best = gs[g]; bi = g; }
      gsel |= 1u << bi;
    }
    unsigned long long taken = 0ull;
    int sel[Kn]; double wv[Kn]; double wsum = 0.0;
    for (int k = 0; k < Kn; ++k) {
      double best = -1e300; int bi = 0;
      for (int ee = 0; ee < En; ++ee) {
        if (!((gsel >> (ee >> 3)) & 1)) continue;
        if ((taken >> ee) & 1) continue;
        double v = sds[ee] + (double)gb[ee];
        if (v > best) { best = v; bi = ee; }
      }
      taken |= 1ull << bi;
      sel[k] = bi;
      wv[k] = sds[bi];
      wsum += wv[k];
    }
    double inv = RSF / (wsum + 1e-20);
    for (int k = 0; k < Kn; ++k) {
      ids[t * Kn + k] = sel[k];
      tw[t * Kn + k] = (float)(wv[k] * inv);
    }
  }
}

// ---------------- dispatch: ballot-rank scan, cumsum position semantics ----------------
__global__ void dispatch_kernel(const int* __restrict__ ids, int* __restrict__ etok,
                                int* __restrict__ ppos, int* __restrict__ ecnt) {
  int e = blockIdx.x;
  int tid = threadIdx.x;
  int lane = tid & 63, wv = tid >> 6;
  __shared__ int wcnt[4];
  int base = 0;
  for (int c = 0; c < Tn * Kn; c += 256) {
    int f = c + tid;
    bool p = (ids[f] == e);
    unsigned long long m = __ballot(p);
    int rank = __popcll(m & ((1ull << lane) - 1ull));
    if (lane == 0) wcnt[wv] = __popcll(m);
    __syncthreads();
    int woff = 0;
    for (int w = 0; w < wv; ++w) woff += wcnt[w];
    int tot = wcnt[0] + wcnt[1] + wcnt[2] + wcnt[3];
    if (p) {
      int pos = base + woff + rank;
      if (pos < Cn) { etok[e * Cn + pos] = f / Kn; ppos[f] = pos; }
      else ppos[f] = -1;
    }
    base += tot;
    __syncthreads();
  }
  int cc = base < Cn ? base : Cn;
  for (int cpos = cc + tid; cpos < Cn; cpos += 256) etok[e * Cn + cpos] = -1;
  if (tid == 0) ecnt[e] = cc;
}

// ---------------- GEMM1 fused: A-fragments direct-from-global, B dbuf in LDS ----------
// 512 threads, 8 waves x 16 rows; BM=128, BN=64(g)+64(u), BK=64.
__global__ __launch_bounds__(512, 4)
void gemm1_fused(const __bf16* __restrict__ A, const int* __restrict__ etok,
                 const int* __restrict__ ecnt, const float* __restrict__ w13,
                 const float* __restrict__ sgu, __bf16* __restrict__ hmid,
                 __bf16* __restrict__ smid) {
  int hw = blockIdx.x;
  int m0, n0, Nhalf;
  const int* rows = nullptr;
  const float* Bp;
  __bf16* Op;
  if (hw < 256) {                      // shared: 8 msegs x 32 ntiles
    m0 = (hw >> 5) * 128; n0 = (hw & 31) * 64;
    Nhalf = Sn; Bp = sgu; Op = smid;
  } else {                             // expert: 8 xcd x 8 e x (16 ntile x 2 mseg adj)
    int ex = hw - 256;
    int xcd = ex & 7, slot = ex >> 3;
    int e = xcd * 8 + (slot >> 5);
    int within = slot & 31;
    m0 = (within & 1) * 128;           // mseg pairs adjacent (hw delta 8, same XCD)
    n0 = (within >> 1) * 64;
    if (ecnt[e] <= m0) return;
    Nhalf = In; Bp = w13 + (size_t)e * Hn * 2 * In;
    Op = hmid + (size_t)e * Cn * In; rows = etok + e * Cn;
  }

  __shared__ __attribute__((aligned(16))) __bf16 Bg[2][64 * 64];
  __shared__ __attribute__((aligned(16))) __bf16 Bu[2][64 * 64];

  int tid = threadIdx.x, lane = tid & 63, wv = tid >> 6;
  int l15 = lane & 15, lhi = lane >> 4;

  // per-lane A row pointer (gathered for experts)
  int cap = m0 + wv * 16 + l15;
  int rix;
  if (rows) { int v = rows[cap]; rix = v < 0 ? 0 : v; }
  else rix = cap;
  const __bf16* pa = A + (size_t)rix * Hn + lhi * 8;

  // B staging: threads 0-255 gate, 256-511 up; 4 k-rows x 4 cols each
  int bt = tid & 255;
  int kb = (bt >> 4) * 4;
  int cB = (bt & 15) * 4;
  size_t ldb = (size_t)2 * Nhalf;
  const float* bsrc = Bp + (size_t)kb * ldb + n0 + cB + (tid >= 256 ? Nhalf : 0);

  f32x4 zero = {0.f, 0.f, 0.f, 0.f};
  f32x4 accg[4], accu[4];
#pragma unroll
  for (int j = 0; j < 4; ++j) { accg[j] = zero; accu[j] = zero; }

  float4 qb[4];
  bf16x8 a00, a01, a10, a11;   // two A banks x two kk frags

#define LOADB1(K0)                                                         \
  { _Pragma("unroll") for (int r = 0; r < 4; ++r)                          \
      qb[r] = *(const float4*)(bsrc + (size_t)((K0) + r) * ldb); }

#define WRITEB1(P)                                                         \
  { __bf16* BtP = (tid >= 256) ? Bu[P] : Bg[P];                            \
    _Pragma("unroll") for (int j = 0; j < 4; ++j) {                        \
      bf16x4 cv;                                                           \
      _Pragma("unroll") for (int r = 0; r < 4; ++r)                        \
        cv[r] = (__bf16)(((const float*)&qb[r])[j]);                       \
      *(bf16x4*)((char*)BtP + swz(cB + j, kb * 2)) = cv;                   \
    } }

#define PREFA1(K0, AK0, AK1)                                               \
  { AK0 = *(const bf16x8*)(pa + (K0));                                     \
    AK1 = *(const bf16x8*)(pa + (K0) + 32); }

#define MFMA1(P, AK0, AK1)                                                 \
  { _Pragma("unroll") for (int n = 0; n < 4; ++n) {                        \
      bf16x8 fg = *(const bf16x8*)((char*)Bg[P] + swz(n * 16 + l15, 16 * lhi));      \
      accg[n] = __builtin_amdgcn_mfma_f32_16x16x32_bf16(AK0, fg, accg[n], 0, 0, 0);  \
      bf16x8 fu = *(const bf16x8*)((char*)Bu[P] + swz(n * 16 + l15, 16 * lhi));      \
      accu[n] = __builtin_amdgcn_mfma_f32_16x16x32_bf16(AK0, fu, accu[n], 0, 0, 0);  \
    }                                                                      \
    _Pragma("unroll") for (int n = 0; n < 4; ++n) {                        \
      bf16x8 fg = *(const bf16x8*)((char*)Bg[P] + swz(n * 16 + l15, 64 + 16 * lhi)); \
      accg[n] = __builtin_amdgcn_mfma_f32_16x16x32_bf16(AK1, fg, accg[n], 0, 0, 0);  \
      bf16x8 fu = *(const bf16x8*)((char*)Bu[P] + swz(n * 16 + l15, 64 + 16 * lhi)); \
      accu[n] = __builtin_amdgcn_mfma_f32_16x16x32_bf16(AK1, fu, accu[n], 0, 0, 0);  \
    } }

  const int nt = Hn >> 6;   // 32, even
  LOADB1(0);
  WRITEB1(0);
  LOADB1(64);
  PREFA1(0, a00, a01);
  BAR();
  for (int t = 0; t < nt; t += 2) {
    // even iter: LDS buf0, A bank0; prefetch bank1
    if (t + 1 < nt) PREFA1((t + 1) << 6, a10, a11);
    __builtin_amdgcn_s_setprio(1);
    MFMA1(0, a00, a01);
    __builtin_amdgcn_s_setprio(0);
    if (t + 1 < nt) {
      WRITEB1(1);
      if (t + 2 < nt) LOADB1((t + 2) << 6);
    }
    BAR();
    // odd iter: LDS buf1, A bank1; prefetch bank0
    if (t + 2 < nt) PREFA1((t + 2) << 6, a00, a01);
    __builtin_amdgcn_s_setprio(1);
    MFMA1(1, a10, a11);
    __builtin_amdgcn_s_setprio(0);
    if (t + 2 < nt) {
      WRITEB1(0);
      if (t + 3 < nt) LOADB1((t + 3) << 6);
    }
    BAR();
  }
#undef LOADB1
#undef WRITEB1
#undef PREFA1
#undef MFMA1

#pragma unroll
  for (int n = 0; n < 4; ++n)
#pragma unroll
    for (int r = 0; r < 4; ++r) {
      int row = m0 + wv * 16 + lhi * 4 + r;
      int col = n0 + n * 16 + l15;
      float g = accg[n][r], u = accu[n][r];
      float v = g / (1.f + __expf(-g)) * u;
      Op[(size_t)row * Nhalf + col] = (__bf16)v;
    }
}

// ---------------- GEMM2 fused: A (bf16 mid) direct-from-global, B dbuf in LDS -------
// 512 threads, 8 waves x 16 rows; BM=128, BN=64. Expert -> y bf16, shared -> out fp32.
__global__ __launch_bounds__(512, 4)
void gemm2_fused(const __bf16* __restrict__ hmid, const __bf16* __restrict__ smid,
                 const float* __restrict__ w2, const float* __restrict__ sdn,
                 const int* __restrict__ ecnt, __bf16* __restrict__ y,
                 float* __restrict__ out) {
  int hw = blockIdx.x;
  int m0, n0, Kd;
  const __bf16* Ap;
  const float* Bp;
  float* dstF = nullptr;
  __bf16* dstB = nullptr;
  if (hw < 256) {                      // shared: 8 msegs x 32 ntiles
    m0 = (hw >> 5) * 128; n0 = (hw & 31) * 64;
    Kd = Sn; Ap = smid; Bp = sdn; dstF = out;
  } else {                             // expert: 8 xcd x 8 e x (32 ntile x 2 mseg adj)
    int ex = hw - 256;
    int xcd = ex & 7, slot = ex >> 3;
    int e = xcd * 8 + (slot >> 6);
    int within = slot & 63;
    m0 = (within & 1) * 128;
    n0 = (within >> 1) * 64;
    if (ecnt[e] <= m0) return;
    Kd = In; Ap = hmid + (size_t)e * Cn * In;
    Bp = w2 + (size_t)e * In * Hn; dstB = y + (size_t)e * Cn * Hn;
  }

  __shared__ __attribute__((aligned(16))) __bf16 Bs[2][64 * 64];

  int tid = threadIdx.x, lane = tid & 63, wv = tid >> 6;
  int l15 = lane & 15, lhi = lane >> 4;

  const __bf16* pa = Ap + (size_t)(m0 + wv * 16 + l15) * Kd + lhi * 8;

  // B staging: threads 0-255 only; 4 k-rows x 4 cols each
  int kb = (tid >> 4) * 4;
  int cB = (tid & 15) * 4;
  const float* bp0 = Bp + (size_t)kb * Hn + n0 + cB;

  f32x4 zero = {0.f, 0.f, 0.f, 0.f};
  f32x4 acc[4];
#pragma unroll
  for (int j = 0; j < 4; ++j) acc[j] = zero;

  float4 qb[4];
  bf16x8 a00, a01, a10, a11;

#define LOADB2(K0)                                                          \
  { if (tid < 256) {                                                        \
      _Pragma("unroll") for (int r = 0; r < 4; ++r)                         \
        qb[r] = *(const float4*)(bp0 + (size_t)((K0) + r) * Hn); } }

#define WRITEB2(P)                                                          \
  { if (tid < 256) {                                                        \
      _Pragma("unroll") for (int j = 0; j < 4; ++j) {                       \
        bf16x4 cv;                                                          \
        _Pragma("unroll") for (int r = 0; r < 4; ++r)                       \
          cv[r] = (__bf16)(((const float*)&qb[r])[j]);                      \
        *(bf16x4*)((char*)Bs[P] + swz(cB + j, kb * 2)) = cv;                \
      } } }

#define PREFA2(K0, AK0, AK1)                                                \
  { AK0 = *(const bf16x8*)(pa + (K0));                                      \
    AK1 = *(const bf16x8*)(pa + (K0) + 32); }

#define MFMA2(P, AK0, AK1)                                                  \
  { _Pragma("unroll") for (int n = 0; n < 4; ++n) {                         \
      bf16x8 fb = *(const bf16x8*)((char*)Bs[P] + swz(n * 16 + l15, 16 * lhi));      \
      acc[n] = __builtin_amdgcn_mfma_f32_16x16x32_bf16(AK0, fb, acc[n], 0, 0, 0);    \
    }                                                                       \
    _Pragma("unroll") for (int n = 0; n < 4; ++n) {                         \
      bf16x8 fb = *(const bf16x8*)((char*)Bs[P] + swz(n * 16 + l15, 64 + 16 * lhi)); \
      acc[n] = __builtin_amdgcn_mfma_f32_16x16x32_bf16(AK1, fb, acc[n], 0, 0, 0);    \
    } }

  const int nt = Kd >> 6;   // 16 or 32, even
  LOADB2(0);
  WRITEB2(0);
  LOADB2(64);
  PREFA2(0, a00, a01);
  BAR();
  for (int t = 0; t < nt; t += 2) {
    if (t + 1 < nt) PREFA2((t + 1) << 6, a10, a11);
    __builtin_amdgcn_s_setprio(1);
    MFMA2(0, a00, a01);
    __builtin_amdgcn_s_setprio(0);
    if (t + 1 < nt) {
      WRITEB2(1);
      if (t + 2 < nt) LOADB2((t + 2) << 6);
    }
    BAR();
    if (t + 2 < nt) PREFA2((t + 2) << 6, a00, a01);
    __builtin_amdgcn_s_setprio(1);
    MFMA2(1, a10, a11);
    __builtin_amdgcn_s_setprio(0);
    if (t + 2 < nt) {
      WRITEB2(0);
      if (t + 3 < nt) LOADB2((t + 3) << 6);
    }
    BAR();
  }
#undef LOADB2
#undef WRITEB2
#undef PREFA2
#undef MFMA2

  if (dstF) {
#pragma unroll
    for (int n = 0; n < 4; ++n)
#pragma unroll
      for (int r = 0; r < 4; ++r) {
        int row = m0 + wv * 16 + lhi * 4 + r;
        int col = n0 + n * 16 + l15;
        dstF[(size_t)row * Hn + col] = acc[n][r];
      }
  } else {
#pragma unroll
    for (int n = 0; n < 4; ++n)
#pragma unroll
      for (int r = 0; r < 4; ++r) {
        int row = m0 + wv * 16 + lhi * 4 + r;
        int col = n0 + n * 16 + l15;
        dstB[(size_t)row * Hn + col] = (__bf16)acc[n][r];
      }
  }
}

// ---------------- combine: out[t] = shared_out[t] + sum_k w_k * y[e_k, pos_k] ----------------
__global__ void combine_kernel(const int* __restrict__ ids, const float* __restrict__ tw,
                               const int* __restrict__ ppos, const __bf16* __restrict__ y,
                               float* __restrict__ out) {
  int t = blockIdx.x;
  int c0 = threadIdx.x * 8;
  float* orow = out + (size_t)t * Hn + c0;
  float4 a0 = *(const float4*)orow;
  float4 a1 = *(const float4*)(orow + 4);
#pragma unroll
  for (int k = 0; k < Kn; ++k) {
    int f = t * Kn + k;
    int p = ppos[f];
    if (p < 0) continue;
    int e = ids[f];
    float w = tw[f];
    bf16x8 bv = *(const bf16x8*)(y + ((size_t)e * Cn + p) * Hn + c0);
    a0.x += w * (float)bv[0]; a0.y += w * (float)bv[1];
    a0.z += w * (float)bv[2]; a0.w += w * (float)bv[3];
    a1.x += w * (float)bv[4]; a1.y += w * (float)bv[5];
    a1.z += w * (float)bv[6]; a1.w += w * (float)bv[7];
  }
  *(float4*)orow = a0;
  *(float4*)(orow + 4) = a1;
}

extern "C" void kernel_launch(void* const* d_in, const int* in_sizes, int n_in,
                              void* d_out, int out_size, void* d_ws, size_t ws_size,
                              hipStream_t stream) {
  (void)in_sizes; (void)n_in; (void)out_size; (void)ws_size;
  const float* x   = (const float*)d_in[0];
  const float* gw  = (const float*)d_in[1];
  const float* gb  = (const float*)d_in[2];
  const float* w13 = (const float*)d_in[3];
  const float* w2  = (const float*)d_in[4];
  const float* sgu = (const float*)d_in[5];
  const float* sdn = (const float*)d_in[6];
  float* out = (float*)d_out;

  char* ws = (char*)d_ws;
  size_t off = 0;
  int* ids   = (int*)(ws + off);   off += (size_t)Tn * Kn * 4;
  float* tw  = (float*)(ws + off); off += (size_t)Tn * Kn * 4;
  int* ppos  = (int*)(ws + off);   off += (size_t)Tn * Kn * 4;
  int* etok  = (int*)(ws + off);   off += (size_t)En * Cn * 4;
  int* ecnt  = (int*)(ws + off);   off += 256;
  __bf16* xbf  = (__bf16*)(ws + off); off += (size_t)Tn * Hn * 2;
  __bf16* hmid = (__bf16*)(ws + off); off += (size_t)En * Cn * In * 2;
  __bf16* smid = (__bf16*)(ws + off); off += (size_t)Tn * Sn * 2;
  __bf16* y    = (__bf16*)(ws + off); off += (size_t)En * Cn * Hn * 2;

  xcvt_kernel<<<Tn * Hn / (256 * 8), 256, 0, stream>>>(x, xbf);
  router_kernel<<<Tn, 64, 0, stream>>>(x, gw, gb, ids, tw);
  dispatch_kernel<<<En, 256, 0, stream>>>(ids, etok, ppos, ecnt);

  // gemm1: 256 shared + 2048 expert blocks (mseg-adjacent, XCD-decomposed)
  gemm1_fused<<<dim3(256 + 2048), 512, 0, stream>>>(xbf, etok, ecnt, w13, sgu, hmid, smid);
  // gemm2: 256 shared (-> out fp32) + 4096 expert (-> y bf16), no atomics
  gemm2_fused<<<dim3(256 + 4096), 512, 0, stream>>>(hmid, smid, w2, sdn, ecnt, y, out);
  // combine: weighted gather of y + shared out
  combine_kernel<<<Tn, 256, 0, stream>>>(ids, tw, ppos, y, out);
}

// Round 9
// 647.829 us; speedup vs baseline: 1.0305x; 1.0305x over previous
//
#include <hip/hip_runtime.h>
#include <hip/hip_bf16.h>
#include <math.h>

#define Tn 1024
#define Hn 2048
#define En 64
#define Kn 6
#define In 1024
#define Gn 8
#define TGn 3
#define Cn 256
#define Sn 2048
#define RSF 2.5

typedef __bf16 bf16x8 __attribute__((ext_vector_type(8)));
typedef __bf16 bf16x4 __attribute__((ext_vector_type(4)));
typedef float f32x4 __attribute__((ext_vector_type(4)));

// swizzled byte offset within a [rows][64 bf16] (128B-row) LDS tile.
__device__ __forceinline__ int swz(int row, int kbyte) {
  return row * 128 + (kbyte ^ ((((row >> 2) ^ row) & 7) << 4));
}

// one barrier per K-step: make LDS writes visible, never drain vmcnt.
#define BAR()                                                  \
  do {                                                         \
    asm volatile("s_waitcnt lgkmcnt(0)" ::: "memory");         \
    __builtin_amdgcn_sched_barrier(0);                         \
    __builtin_amdgcn_s_barrier();                              \
    __builtin_amdgcn_sched_barrier(0);                         \
  } while (0)

// ---------------- x -> bf16 pre-pass ----------------
__global__ void xcvt_kernel(const float* __restrict__ x, __bf16* __restrict__ xbf) {
  int i = (blockIdx.x * 256 + threadIdx.x) * 8;
  float4 v0 = *(const float4*)(x + i);
  float4 v1 = *(const float4*)(x + i + 4);
  bf16x8 h;
  h[0] = (__bf16)v0.x; h[1] = (__bf16)v0.y; h[2] = (__bf16)v0.z; h[3] = (__bf16)v0.w;
  h[4] = (__bf16)v1.x; h[5] = (__bf16)v1.y; h[6] = (__bf16)v1.z; h[7] = (__bf16)v1.w;
  *(bf16x8*)(xbf + i) = h;
}

// ---------------- router: sigmoid(x @ gate_w^T) in fp64 + grouped top-k ----------------
__global__ void router_kernel(const float* __restrict__ x, const float* __restrict__ gw,
                              const float* __restrict__ gb, int* __restrict__ ids,
                              float* __restrict__ tw) {
  __shared__ float xs[Hn];
  __shared__ double sds[En];
  __shared__ double gs[Gn];
  int t = blockIdx.x;
  for (int i = threadIdx.x * 4; i < Hn; i += 64 * 4)
    *(float4*)(xs + i) = *(const float4*)(x + (size_t)t * Hn + i);
  __syncthreads();
  int e = threadIdx.x;
  const float* w = gw + (size_t)e * Hn;
  double a0 = 0.0, a1 = 0.0, a2 = 0.0, a3 = 0.0;
  for (int i = 0; i < Hn; i += 4) {
    float4 b = *(const float4*)(w + i);
    a0 += (double)xs[i] * b.x;
    a1 += (double)xs[i + 1] * b.y;
    a2 += (double)xs[i + 2] * b.z;
    a3 += (double)xs[i + 3] * b.w;
  }
  double acc = (a0 + a1) + (a2 + a3);
  sds[e] = 1.0 / (1.0 + exp(-acc));
  __syncthreads();
  if (e < Gn) {
    double m1 = -1e300, m2 = -1e300;
    for (int j = 0; j < 8; ++j) {
      double v = sds[e * 8 + j] + (double)gb[e * 8 + j];
      if (v > m1) { m2 = m1; m1 = v; } else if (v > m2) m2 = v;
    }
    gs[e] = m1 + m2;
  }
  __syncthreads();
  if (e == 0) {
    unsigned gsel = 0;
    for (int it = 0; it < TGn; ++it) {
      double best = -1e300; int bi = 0;
      for (int g = 0; g < Gn; ++g)
        if (!((gsel >> g) & 1) && gs[g] > best) { best = gs[g]; bi = g; }
      gsel |= 1u << bi;
    }
    unsigned long long taken = 0ull;
    int sel[Kn]; double wv[Kn]; double wsum = 0.0;
    for (int k = 0; k < Kn; ++k) {
      double best = -1e300; int bi = 0;
      for (int ee = 0; ee < En; ++ee) {
        if (!((gsel >> (ee >> 3)) & 1)) continue;
        if ((taken >> ee) & 1) continue;
        double v = sds[ee] + (double)gb[ee];
        if (v > best) { best = v; bi = ee; }
      }
      taken |= 1ull << bi;
      sel[k] = bi;
      wv[k] = sds[bi];
      wsum += wv[k];
    }
    double inv = RSF / (wsum + 1e-20);
    for (int k = 0; k < Kn; ++k) {
      ids[t * Kn + k] = sel[k];
      tw[t * Kn + k] = (float)(wv[k] * inv);
    }
  }
}

// ---------------- dispatch: ballot-rank scan, cumsum position semantics ----------------
__global__ void dispatch_kernel(const int* __restrict__ ids, int* __restrict__ etok,
                                int* __restrict__ ppos, int* __restrict__ ecnt) {
  int e = blockIdx.x;
  int tid = threadIdx.x;
  int lane = tid & 63, wv = tid >> 6;
  __shared__ int wcnt[4];
  int base = 0;
  for (int c = 0; c < Tn * Kn; c += 256) {
    int f = c + tid;
    bool p = (ids[f] == e);
    unsigned long long m = __ballot(p);
    int rank = __popcll(m & ((1ull << lane) - 1ull));
    if (lane == 0) wcnt[wv] = __popcll(m);
    __syncthreads();
    int woff = 0;
    for (int w = 0; w < wv; ++w) woff += wcnt[w];
    int tot = wcnt[0] + wcnt[1] + wcnt[2] + wcnt[3];
    if (p) {
      int pos = base + woff + rank;
      if (pos < Cn) { etok[e * Cn + pos] = f / Kn; ppos[f] = pos; }
      else ppos[f] = -1;
    }
    base += tot;
    __syncthreads();
  }
  int cc = base < Cn ? base : Cn;
  for (int cpos = cc + tid; cpos < Cn; cpos += 256) etok[e * Cn + cpos] = -1;
  if (tid == 0) ecnt[e] = cc;
}

// ---------------- GEMM1 fused (expert + shared): xbf @ W13 / sgu, SiLU*mul, bf16 out ----
// 512 threads (8 waves x 16-row tiles), BM=128, BN=64(g)+64(u), BK=64, dbuf LDS.
// B-stream prefetch depth 2 phases (banks qbA/qbB); A (L2-resident) depth 1.
__global__ __launch_bounds__(512, 4)
void gemm1_fused(const __bf16* __restrict__ A, const int* __restrict__ etok,
                 const int* __restrict__ ecnt, const float* __restrict__ w13,
                 const float* __restrict__ sgu, __bf16* __restrict__ hmid,
                 __bf16* __restrict__ smid) {
  int hw = blockIdx.x;
  int m0, n0, Nhalf;
  const int* rows = nullptr;
  const float* Bp;
  __bf16* Op;
  if (hw < 256) {                      // shared: 8 msegs x 32 ntiles
    m0 = (hw >> 5) * 128; n0 = (hw & 31) * 64;
    Nhalf = Sn; Bp = sgu; Op = smid;
  } else {                             // expert: 8 xcd x 8 e x (2 mseg x 16 ntile)
    int ex = hw - 256;
    int xcd = ex & 7, slot = ex >> 3;
    int e = xcd * 8 + (slot >> 5);
    int within = slot & 31;
    m0 = (within >> 4) * 128; n0 = (within & 15) * 64;
    if (ecnt[e] <= m0) return;
    Nhalf = In; Bp = w13 + (size_t)e * Hn * 2 * In;
    Op = hmid + (size_t)e * Cn * In; rows = etok + e * Cn;
  }

  __shared__ __attribute__((aligned(16))) __bf16 As[2][128 * 64];
  __shared__ __attribute__((aligned(16))) __bf16 Bg[2][64 * 64];
  __shared__ __attribute__((aligned(16))) __bf16 Bu[2][64 * 64];
  __shared__ int rowix[128];

  int tid = threadIdx.x;
  if (tid < 128) {
    int r;
    if (rows) { int v = rows[m0 + tid]; r = v < 0 ? 0 : v; }
    else r = m0 + tid;
    rowix[tid] = r;
  }
  __syncthreads();

  int lane = tid & 63;
  int wv = tid >> 6;                 // 0..7, wave owns rows [16*wv, 16*wv+16)
  int l15 = lane & 15, lhi = lane >> 4;

  int rowA = tid >> 3, kc8 = (tid & 7) * 8, kcB = (tid & 7) * 16;
  const __bf16* arow0 = A + (size_t)rowix[rowA] * Hn + kc8;
  const __bf16* arow1 = A + (size_t)rowix[rowA + 64] * Hn + kc8;

  int bt = tid & 255;
  int kb = (bt >> 4) * 4;
  int cB = (bt & 15) * 4;
  size_t ldb = (size_t)2 * Nhalf;
  const float* bsrc = Bp + (size_t)kb * ldb + n0 + cB + (tid >= 256 ? Nhalf : 0);

  f32x4 zero = {0.f, 0.f, 0.f, 0.f};
  f32x4 accg[4], accu[4];
#pragma unroll
  for (int j = 0; j < 4; ++j) { accg[j] = zero; accu[j] = zero; }

  bf16x8 qa0, qa1;
  float4 qbA[4], qbB[4];

#define LOADA1(K0)                                                         \
  { qa0 = *(const bf16x8*)(arow0 + (K0));                                  \
    qa1 = *(const bf16x8*)(arow1 + (K0)); }

#define LOADB1(K0, QB)                                                     \
  { _Pragma("unroll") for (int r = 0; r < 4; ++r)                          \
      QB[r] = *(const float4*)(bsrc + (size_t)((K0) + r) * ldb); }

#define WRITE1(P, QB)                                                      \
  {                                                                        \
    *(bf16x8*)((char*)As[P] + swz(rowA, kcB)) = qa0;                       \
    *(bf16x8*)((char*)As[P] + swz(rowA + 64, kcB)) = qa1;                  \
    __bf16* BtP = (tid >= 256) ? Bu[P] : Bg[P];                            \
    _Pragma("unroll") for (int j = 0; j < 4; ++j) {                        \
      bf16x4 cv;                                                           \
      _Pragma("unroll") for (int r = 0; r < 4; ++r)                        \
        cv[r] = (__bf16)(((const float*)&QB[r])[j]);                       \
      *(bf16x4*)((char*)BtP + swz(cB + j, kb * 2)) = cv;                   \
    }                                                                      \
  }

#define MFMA1(P)                                                           \
  _Pragma("unroll") for (int kk = 0; kk < 2; ++kk) {                       \
    int kbyte = kk * 64 + 16 * lhi;                                        \
    bf16x8 af = *(const bf16x8*)((char*)As[P] + swz(wv * 16 + l15, kbyte));\
    _Pragma("unroll") for (int n = 0; n < 4; ++n) {                        \
      bf16x8 fg = *(const bf16x8*)((char*)Bg[P] + swz(n * 16 + l15, kbyte)); \
      accg[n] = __builtin_amdgcn_mfma_f32_16x16x32_bf16(af, fg, accg[n], 0, 0, 0); \
      bf16x8 fu = *(const bf16x8*)((char*)Bu[P] + swz(n * 16 + l15, kbyte)); \
      accu[n] = __builtin_amdgcn_mfma_f32_16x16x32_bf16(af, fu, accu[n], 0, 0, 0); \
    }                                                                      \
  }

  const int nt = Hn >> 6;   // 32
  // prologue: steps 0,1,2 of B in flight; step0 staged
  LOADA1(0);
  LOADB1(0, qbA);
  LOADB1(64, qbB);
  WRITE1(0, qbA);            // one-time stall on step0 loads
  LOADA1(64);
  LOADB1(128, qbA);          // step2 -> bank A
  BAR();
  for (int t = 0; t < nt; ++t) {
    int p = t & 1;
    __builtin_amdgcn_s_setprio(1);
    MFMA1(p);
    __builtin_amdgcn_s_setprio(0);
    if (t + 1 < nt) {
      if ((t + 1) & 1) { WRITE1(p ^ 1, qbB); } else { WRITE1(p ^ 1, qbA); }
      if (t + 2 < nt) LOADA1((t + 2) << 6);
      if (t + 3 < nt) {
        if ((t + 3) & 1) { LOADB1((t + 3) << 6, qbB); }
        else             { LOADB1((t + 3) << 6, qbA); }
      }
    }
    BAR();
  }
#undef LOADA1
#undef LOADB1
#undef WRITE1
#undef MFMA1

#pragma unroll
  for (int n = 0; n < 4; ++n)
#pragma unroll
    for (int r = 0; r < 4; ++r) {
      int row = m0 + wv * 16 + lhi * 4 + r;
      int col = n0 + n * 16 + l15;
      float g = accg[n][r], u = accu[n][r];
      float v = g / (1.f + __expf(-g)) * u;
      Op[(size_t)row * Nhalf + col] = (__bf16)v;
    }
}

// ---------------- GEMM2 fused (expert + shared): plain stores, NO atomics ----------------
// 256 threads (4 waves x 32-row tiles), BM=128, BN=64, dbuf LDS, B depth-2 prefetch.
__global__ __launch_bounds__(256, 4)
void gemm2_fused(const __bf16* __restrict__ hmid, const __bf16* __restrict__ smid,
                 const float* __restrict__ w2, const float* __restrict__ sdn,
                 const int* __restrict__ ecnt, __bf16* __restrict__ y,
                 float* __restrict__ out) {
  int hw = blockIdx.x;
  int m0, n0, Kd;
  const __bf16* Ap;
  const float* Bp;
  float* dstF = nullptr;
  __bf16* dstB = nullptr;
  if (hw < 256) {                      // shared: 8 msegs x 32 ntiles
    m0 = (hw >> 5) * 128; n0 = (hw & 31) * 64;
    Kd = Sn; Ap = smid; Bp = sdn; dstF = out;
  } else {                             // expert: 8 xcd x 8 e x (2 mseg x 32 ntile)
    int ex = hw - 256;
    int xcd = ex & 7, slot = ex >> 3;
    int e = xcd * 8 + (slot >> 6);
    int within = slot & 63;
    m0 = (within >> 5) * 128; n0 = (within & 31) * 64;
    if (ecnt[e] <= m0) return;
    Kd = In; Ap = hmid + (size_t)e * Cn * In;
    Bp = w2 + (size_t)e * In * Hn; dstB = y + (size_t)e * Cn * Hn;
  }

  __shared__ __attribute__((aligned(16))) __bf16 As[2][128 * 64];
  __shared__ __attribute__((aligned(16))) __bf16 Bs[2][64 * 64];

  int tid = threadIdx.x;
  int lane = tid & 63;
  int wr = tid >> 6;
  int l15 = lane & 15, lhi = lane >> 4;

  int rowA = tid >> 3, kc8 = (tid & 7) * 8;
  const __bf16* ap0 = Ap + (size_t)(m0 + rowA) * Kd + kc8;

  int kb = (tid >> 4) * 4;
  int cB = (tid & 15) * 4;
  const float* bp0 = Bp + (size_t)kb * Hn + n0 + cB;

  f32x4 zero = {0.f, 0.f, 0.f, 0.f};
  f32x4 acc[2][4];
#pragma unroll
  for (int i = 0; i < 2; ++i)
#pragma unroll
    for (int j = 0; j < 4; ++j) acc[i][j] = zero;

  bf16x8 qa[4];
  float4 qbA[4], qbB[4];

#define LOADA2(K0)                                                          \
  { _Pragma("unroll") for (int it = 0; it < 4; ++it)                        \
      qa[it] = *(const bf16x8*)(ap0 + (size_t)(32 * it) * Kd + (K0)); }

#define LOADB2(K0, QB)                                                      \
  { _Pragma("unroll") for (int r = 0; r < 4; ++r)                           \
      QB[r] = *(const float4*)(bp0 + (size_t)((K0) + r) * Hn); }

#define WRITE2(P, QB)                                                       \
  {                                                                         \
    _Pragma("unroll") for (int it = 0; it < 4; ++it)                        \
      *(bf16x8*)((char*)As[P] + swz(rowA + 32 * it, kc8 * 2)) = qa[it];     \
    _Pragma("unroll") for (int j = 0; j < 4; ++j) {                         \
      bf16x4 cv;                                                            \
      _Pragma("unroll") for (int r = 0; r < 4; ++r)                         \
        cv[r] = (__bf16)(((const float*)&QB[r])[j]);                        \
      *(bf16x4*)((char*)Bs[P] + swz(cB + j, kb * 2)) = cv;                  \
    }                                                                       \
  }

#define MFMA2(P)                                                            \
  _Pragma("unroll") for (int kk = 0; kk < 2; ++kk) {                        \
    int kbyte = kk * 64 + 16 * lhi;                                         \
    bf16x8 af0 = *(const bf16x8*)((char*)As[P] + swz(wr * 32 + l15, kbyte));       \
    bf16x8 af1 = *(const bf16x8*)((char*)As[P] + swz(wr * 32 + 16 + l15, kbyte));  \
    _Pragma("unroll") for (int n = 0; n < 4; ++n) {                         \
      bf16x8 bfr = *(const bf16x8*)((char*)Bs[P] + swz(n * 16 + l15, kbyte));      \
      acc[0][n] = __builtin_amdgcn_mfma_f32_16x16x32_bf16(af0, bfr, acc[0][n], 0, 0, 0); \
      acc[1][n] = __builtin_amdgcn_mfma_f32_16x16x32_bf16(af1, bfr, acc[1][n], 0, 0, 0); \
    }                                                                       \
  }

  int nt = Kd >> 6;
  LOADA2(0);
  LOADB2(0, qbA);
  LOADB2(64, qbB);
  WRITE2(0, qbA);            // one-time stall
  LOADA2(64);
  LOADB2(128, qbA);          // step2 -> bank A
  BAR();
  for (int t = 0; t < nt; ++t) {
    int p = t & 1;
    __builtin_amdgcn_s_setprio(1);
    MFMA2(p);
    __builtin_amdgcn_s_setprio(0);
    if (t + 1 < nt) {
      if ((t + 1) & 1) { WRITE2(p ^ 1, qbB); } else { WRITE2(p ^ 1, qbA); }
      if (t + 2 < nt) LOADA2((t + 2) << 6);
      if (t + 3 < nt) {
        if ((t + 3) & 1) { LOADB2((t + 3) << 6, qbB); }
        else             { LOADB2((t + 3) << 6, qbA); }
      }
    }
    BAR();
  }
#undef LOADA2
#undef LOADB2
#undef WRITE2
#undef MFMA2

  if (dstF) {
#pragma unroll
    for (int m = 0; m < 2; ++m)
#pragma unroll
      for (int n = 0; n < 4; ++n)
#pragma unroll
        for (int r = 0; r < 4; ++r) {
          int lrow = wr * 32 + m * 16 + lhi * 4 + r;
          int col = n0 + n * 16 + l15;
          dstF[(size_t)(m0 + lrow) * Hn + col] = acc[m][n][r];
        }
  } else {
#pragma unroll
    for (int m = 0; m < 2; ++m)
#pragma unroll
      for (int n = 0; n < 4; ++n)
#pragma unroll
        for (int r = 0; r < 4; ++r) {
          int lrow = wr * 32 + m * 16 + lhi * 4 + r;
          int col = n0 + n * 16 + l15;
          dstB[(size_t)(m0 + lrow) * Hn + col] = (__bf16)acc[m][n][r];
        }
  }
}

// ---------------- combine: out[t] = shared_out[t] + sum_k w_k * y[e_k, pos_k] ----------------
__global__ void combine_kernel(const int* __restrict__ ids, const float* __restrict__ tw,
                               const int* __restrict__ ppos, const __bf16* __restrict__ y,
                               float* __restrict__ out) {
  int t = blockIdx.x;
  int c0 = threadIdx.x * 8;
  float* orow = out + (size_t)t * Hn + c0;
  float4 a0 = *(const float4*)orow;
  float4 a1 = *(const float4*)(orow + 4);
#pragma unroll
  for (int k = 0; k < Kn; ++k) {
    int f = t * Kn + k;
    int p = ppos[f];
    if (p < 0) continue;
    int e = ids[f];
    float w = tw[f];
    bf16x8 bv = *(const bf16x8*)(y + ((size_t)e * Cn + p) * Hn + c0);
    a0.x += w * (float)bv[0]; a0.y += w * (float)bv[1];
    a0.z += w * (float)bv[2]; a0.w += w * (float)bv[3];
    a1.x += w * (float)bv[4]; a1.y += w * (float)bv[5];
    a1.z += w * (float)bv[6]; a1.w += w * (float)bv[7];
  }
  *(float4*)orow = a0;
  *(float4*)(orow + 4) = a1;
}

extern "C" void kernel_launch(void* const* d_in, const int* in_sizes, int n_in,
                              void* d_out, int out_size, void* d_ws, size_t ws_size,
                              hipStream_t stream) {
  (void)in_sizes; (void)n_in; (void)out_size; (void)ws_size;
  const float* x   = (const float*)d_in[0];
  const float* gw  = (const float*)d_in[1];
  const float* gb  = (const float*)d_in[2];
  const float* w13 = (const float*)d_in[3];
  const float* w2  = (const float*)d_in[4];
  const float* sgu = (const float*)d_in[5];
  const float* sdn = (const float*)d_in[6];
  float* out = (float*)d_out;

  char* ws = (char*)d_ws;
  size_t off = 0;
  int* ids   = (int*)(ws + off);   off += (size_t)Tn * Kn * 4;
  float* tw  = (float*)(ws + off); off += (size_t)Tn * Kn * 4;
  int* ppos  = (int*)(ws + off);   off += (size_t)Tn * Kn * 4;
  int* etok  = (int*)(ws + off);   off += (size_t)En * Cn * 4;
  int* ecnt  = (int*)(ws + off);   off += 256;
  __bf16* xbf  = (__bf16*)(ws + off); off += (size_t)Tn * Hn * 2;
  __bf16* hmid = (__bf16*)(ws + off); off += (size_t)En * Cn * In * 2;
  __bf16* smid = (__bf16*)(ws + off); off += (size_t)Tn * Sn * 2;
  __bf16* y    = (__bf16*)(ws + off); off += (size_t)En * Cn * Hn * 2;

  xcvt_kernel<<<Tn * Hn / (256 * 8), 256, 0, stream>>>(x, xbf);
  router_kernel<<<Tn, 64, 0, stream>>>(x, gw, gb, ids, tw);
  dispatch_kernel<<<En, 256, 0, stream>>>(ids, etok, ppos, ecnt);

  // gemm1: 256 shared + 2048 expert blocks (XCD-decomposed)
  gemm1_fused<<<dim3(256 + 2048), 512, 0, stream>>>(xbf, etok, ecnt, w13, sgu, hmid, smid);
  // gemm2: 256 shared (-> out fp32) + 4096 expert (-> y bf16), no atomics
  gemm2_fused<<<dim3(256 + 4096), 256, 0, stream>>>(hmid, smid, w2, sdn, ecnt, y, out);
  // combine: weighted gather of y + shared out
  combine_kernel<<<Tn, 256, 0, stream>>>(ids, tw, ppos, y, out);
}

// Round 10
// 643.806 us; speedup vs baseline: 1.0369x; 1.0062x over previous
//
#include <hip/hip_runtime.h>
#include <hip/hip_bf16.h>
#include <math.h>

#define Tn 1024
#define Hn 2048
#define En 64
#define Kn 6
#define In 1024
#define Gn 8
#define TGn 3
#define Cn 256
#define Sn 2048
#define RSF 2.5

typedef __bf16 bf16x8 __attribute__((ext_vector_type(8)));
typedef __bf16 bf16x4 __attribute__((ext_vector_type(4)));
typedef float f32x4 __attribute__((ext_vector_type(4)));

// swizzled byte offset within a [rows][64 bf16] (128B-row) LDS tile.
__device__ __forceinline__ int swz(int row, int kbyte) {
  return row * 128 + (kbyte ^ ((((row >> 2) ^ row) & 7) << 4));
}

// one barrier per K-step: make LDS writes visible, never drain vmcnt.
#define BAR()                                                  \
  do {                                                         \
    asm volatile("s_waitcnt lgkmcnt(0)" ::: "memory");         \
    __builtin_amdgcn_sched_barrier(0);                         \
    __builtin_amdgcn_s_barrier();                              \
    __builtin_amdgcn_sched_barrier(0);                         \
  } while (0)

// ---------------- x -> bf16 pre-pass ----------------
__global__ void xcvt_kernel(const float* __restrict__ x, __bf16* __restrict__ xbf) {
  int i = (blockIdx.x * 256 + threadIdx.x) * 8;
  float4 v0 = *(const float4*)(x + i);
  float4 v1 = *(const float4*)(x + i + 4);
  bf16x8 h;
  h[0] = (__bf16)v0.x; h[1] = (__bf16)v0.y; h[2] = (__bf16)v0.z; h[3] = (__bf16)v0.w;
  h[4] = (__bf16)v1.x; h[5] = (__bf16)v1.y; h[6] = (__bf16)v1.z; h[7] = (__bf16)v1.w;
  *(bf16x8*)(xbf + i) = h;
}

// ---------------- router: sigmoid(x @ gate_w^T) in fp64 + grouped top-k ----------------
__global__ void router_kernel(const float* __restrict__ x, const float* __restrict__ gw,
                              const float* __restrict__ gb, int* __restrict__ ids,
                              float* __restrict__ tw) {
  __shared__ float xs[Hn];
  __shared__ double sds[En];
  __shared__ double gs[Gn];
  int t = blockIdx.x;
  for (int i = threadIdx.x * 4; i < Hn; i += 64 * 4)
    *(float4*)(xs + i) = *(const float4*)(x + (size_t)t * Hn + i);
  __syncthreads();
  int e = threadIdx.x;
  const float* w = gw + (size_t)e * Hn;
  double a0 = 0.0, a1 = 0.0, a2 = 0.0, a3 = 0.0;
  for (int i = 0; i < Hn; i += 4) {
    float4 b = *(const float4*)(w + i);
    a0 += (double)xs[i] * b.x;
    a1 += (double)xs[i + 1] * b.y;
    a2 += (double)xs[i + 2] * b.z;
    a3 += (double)xs[i + 3] * b.w;
  }
  double acc = (a0 + a1) + (a2 + a3);
  sds[e] = 1.0 / (1.0 + exp(-acc));
  __syncthreads();
  if (e < Gn) {
    double m1 = -1e300, m2 = -1e300;
    for (int j = 0; j < 8; ++j) {
      double v = sds[e * 8 + j] + (double)gb[e * 8 + j];
      if (v > m1) { m2 = m1; m1 = v; } else if (v > m2) m2 = v;
    }
    gs[e] = m1 + m2;
  }
  __syncthreads();
  if (e == 0) {
    unsigned gsel = 0;
    for (int it = 0; it < TGn; ++it) {
      double best = -1e300; int bi = 0;
      for (int g = 0; g < Gn; ++g)
        if (!((gsel >> g) & 1) && gs[g] > best) { best = gs[g]; bi = g; }
      gsel |= 1u << bi;
    }
    unsigned long long taken = 0ull;
    int sel[Kn]; double wv[Kn]; double wsum = 0.0;
    for (int k = 0; k < Kn; ++k) {
      double best = -1e300; int bi = 0;
      for (int ee = 0; ee < En; ++ee) {
        if (!((gsel >> (ee >> 3)) & 1)) continue;
        if ((taken >> ee) & 1) continue;
        double v = sds[ee] + (double)gb[ee];
        if (v > best) { best = v; bi = ee; }
      }
      taken |= 1ull << bi;
      sel[k] = bi;
      wv[k] = sds[bi];
      wsum += wv[k];
    }
    double inv = RSF / (wsum + 1e-20);
    for (int k = 0; k < Kn; ++k) {
      ids[t * Kn + k] = sel[k];
      tw[t * Kn + k] = (float)(wv[k] * inv);
    }
  }
}

// ---------------- dispatch: ballot-rank scan, cumsum position semantics ----------------
__global__ void dispatch_kernel(const int* __restrict__ ids, int* __restrict__ etok,
                                int* __restrict__ ppos, int* __restrict__ ecnt) {
  int e = blockIdx.x;
  int tid = threadIdx.x;
  int lane = tid & 63, wv = tid >> 6;
  __shared__ int wcnt[4];
  int base = 0;
  for (int c = 0; c < Tn * Kn; c += 256) {
    int f = c + tid;
    bool p = (ids[f] == e);
    unsigned long long m = __ballot(p);
    int rank = __popcll(m & ((1ull << lane) - 1ull));
    if (lane == 0) wcnt[wv] = __popcll(m);
    __syncthreads();
    int woff = 0;
    for (int w = 0; w < wv; ++w) woff += wcnt[w];
    int tot = wcnt[0] + wcnt[1] + wcnt[2] + wcnt[3];
    if (p) {
      int pos = base + woff + rank;
      if (pos < Cn) { etok[e * Cn + pos] = f / Kn; ppos[f] = pos; }
      else ppos[f] = -1;
    }
    base += tot;
    __syncthreads();
  }
  int cc = base < Cn ? base : Cn;
  for (int cpos = cc + tid; cpos < Cn; cpos += 256) etok[e * Cn + cpos] = -1;
  if (tid == 0) ecnt[e] = cc;
}

// ---------------- GEMM1 fused (expert + shared): xbf @ W13 / sgu, SiLU*mul, bf16 out ----
// 512 threads (8 waves x 16-row tiles), BM=128, BN=64(g)+64(u), BK=64, dbuf LDS.
// Expert decompose: mseg pairs ADJACENT in dispatch (hw, hw+8 -> same XCD,
// co-resident) so the 2nd mseg's B panel hits L2 instead of HBM.
__global__ __launch_bounds__(512, 4)
void gemm1_fused(const __bf16* __restrict__ A, const int* __restrict__ etok,
                 const int* __restrict__ ecnt, const float* __restrict__ w13,
                 const float* __restrict__ sgu, __bf16* __restrict__ hmid,
                 __bf16* __restrict__ smid) {
  int hw = blockIdx.x;
  int m0, n0, Nhalf;
  const int* rows = nullptr;
  const float* Bp;
  __bf16* Op;
  if (hw < 256) {                      // shared: 8 msegs x 32 ntiles (same-ntile msegs on one XCD)
    m0 = (hw >> 5) * 128; n0 = (hw & 31) * 64;
    Nhalf = Sn; Bp = sgu; Op = smid;
  } else {                             // expert: 8 xcd x 8 e x (16 ntile x 2 mseg-adjacent)
    int ex = hw - 256;
    int xcd = ex & 7, slot = ex >> 3;
    int e = xcd * 8 + (slot >> 5);
    int within = slot & 31;
    m0 = (within & 1) * 128;           // pair (hw, hw+8): same ntile, both msegs
    n0 = (within >> 1) * 64;
    if (ecnt[e] <= m0) return;
    Nhalf = In; Bp = w13 + (size_t)e * Hn * 2 * In;
    Op = hmid + (size_t)e * Cn * In; rows = etok + e * Cn;
  }

  __shared__ __attribute__((aligned(16))) __bf16 As[2][128 * 64];
  __shared__ __attribute__((aligned(16))) __bf16 Bg[2][64 * 64];
  __shared__ __attribute__((aligned(16))) __bf16 Bu[2][64 * 64];
  __shared__ int rowix[128];

  int tid = threadIdx.x;
  if (tid < 128) {
    int r;
    if (rows) { int v = rows[m0 + tid]; r = v < 0 ? 0 : v; }
    else r = m0 + tid;
    rowix[tid] = r;
  }
  __syncthreads();

  int lane = tid & 63;
  int wv = tid >> 6;                 // 0..7, wave owns rows [16*wv, 16*wv+16)
  int l15 = lane & 15, lhi = lane >> 4;

  int rowA = tid >> 3, kc8 = (tid & 7) * 8, kcB = (tid & 7) * 16;
  const __bf16* arow0 = A + (size_t)rowix[rowA] * Hn + kc8;
  const __bf16* arow1 = A + (size_t)rowix[rowA + 64] * Hn + kc8;

  int bt = tid & 255;
  int kb = (bt >> 4) * 4;
  int cB = (bt & 15) * 4;
  size_t ldb = (size_t)2 * Nhalf;
  const float* bsrc = Bp + (size_t)kb * ldb + n0 + cB + (tid >= 256 ? Nhalf : 0);

  f32x4 zero = {0.f, 0.f, 0.f, 0.f};
  f32x4 accg[4], accu[4];
#pragma unroll
  for (int j = 0; j < 4; ++j) { accg[j] = zero; accu[j] = zero; }

  bf16x8 qa0, qa1;
  float4 qb[4];

#define LOADS1(K0)                                                         \
  {                                                                        \
    qa0 = *(const bf16x8*)(arow0 + (K0));                                  \
    qa1 = *(const bf16x8*)(arow1 + (K0));                                  \
    _Pragma("unroll") for (int r = 0; r < 4; ++r)                          \
      qb[r] = *(const float4*)(bsrc + (size_t)((K0) + r) * ldb);           \
  }

#define WRITE1(P)                                                          \
  {                                                                        \
    *(bf16x8*)((char*)As[P] + swz(rowA, kcB)) = qa0;                       \
    *(bf16x8*)((char*)As[P] + swz(rowA + 64, kcB)) = qa1;                  \
    __bf16* BtP = (tid >= 256) ? Bu[P] : Bg[P];                            \
    _Pragma("unroll") for (int j = 0; j < 4; ++j) {                        \
      bf16x4 cv;                                                           \
      _Pragma("unroll") for (int r = 0; r < 4; ++r)                        \
        cv[r] = (__bf16)(((const float*)&qb[r])[j]);                       \
      *(bf16x4*)((char*)BtP + swz(cB + j, kb * 2)) = cv;                   \
    }                                                                      \
  }

#define MFMA1(P)                                                           \
  _Pragma("unroll") for (int kk = 0; kk < 2; ++kk) {                       \
    int kbyte = kk * 64 + 16 * lhi;                                        \
    bf16x8 af = *(const bf16x8*)((char*)As[P] + swz(wv * 16 + l15, kbyte));\
    _Pragma("unroll") for (int n = 0; n < 4; ++n) {                        \
      bf16x8 fg = *(const bf16x8*)((char*)Bg[P] + swz(n * 16 + l15, kbyte)); \
      accg[n] = __builtin_amdgcn_mfma_f32_16x16x32_bf16(af, fg, accg[n], 0, 0, 0); \
      bf16x8 fu = *(const bf16x8*)((char*)Bu[P] + swz(n * 16 + l15, kbyte)); \
      accu[n] = __builtin_amdgcn_mfma_f32_16x16x32_bf16(af, fu, accu[n], 0, 0, 0); \
    }                                                                      \
  }

  const int nt = Hn >> 6;   // 32
  LOADS1(0);
  WRITE1(0);
  LOADS1(64);
  BAR();
  for (int t = 0; t < nt; ++t) {
    int p = t & 1;
    __builtin_amdgcn_s_setprio(1);
    MFMA1(p);
    __builtin_amdgcn_s_setprio(0);
    if (t + 1 < nt) {
      WRITE1(p ^ 1);
      if (t + 2 < nt) LOADS1((t + 2) << 6);
    }
    BAR();
  }
#undef LOADS1
#undef WRITE1
#undef MFMA1

#pragma unroll
  for (int n = 0; n < 4; ++n)
#pragma unroll
    for (int r = 0; r < 4; ++r) {
      int row = m0 + wv * 16 + lhi * 4 + r;
      int col = n0 + n * 16 + l15;
      float g = accg[n][r], u = accu[n][r];
      float v = g / (1.f + __expf(-g)) * u;
      Op[(size_t)row * Nhalf + col] = (__bf16)v;
    }
}

// ---------------- GEMM2 fused (expert + shared): plain stores, NO atomics ----------------
// 256 threads (4 waves x 32-row tiles), BM=128, BN=64, dbuf pipeline.
// Expert decompose: mseg pairs adjacent (hw, hw+8) for L2 reuse of w2 panels.
__global__ __launch_bounds__(256, 4)
void gemm2_fused(const __bf16* __restrict__ hmid, const __bf16* __restrict__ smid,
                 const float* __restrict__ w2, const float* __restrict__ sdn,
                 const int* __restrict__ ecnt, __bf16* __restrict__ y,
                 float* __restrict__ out) {
  int hw = blockIdx.x;
  int m0, n0, Kd;
  const __bf16* Ap;
  const float* Bp;
  float* dstF = nullptr;
  __bf16* dstB = nullptr;
  if (hw < 256) {                      // shared: 8 msegs x 32 ntiles
    m0 = (hw >> 5) * 128; n0 = (hw & 31) * 64;
    Kd = Sn; Ap = smid; Bp = sdn; dstF = out;
  } else {                             // expert: 8 xcd x 8 e x (32 ntile x 2 mseg-adjacent)
    int ex = hw - 256;
    int xcd = ex & 7, slot = ex >> 3;
    int e = xcd * 8 + (slot >> 6);
    int within = slot & 63;
    m0 = (within & 1) * 128;
    n0 = (within >> 1) * 64;
    if (ecnt[e] <= m0) return;
    Kd = In; Ap = hmid + (size_t)e * Cn * In;
    Bp = w2 + (size_t)e * In * Hn; dstB = y + (size_t)e * Cn * Hn;
  }

  __shared__ __attribute__((aligned(16))) __bf16 As[2][128 * 64];
  __shared__ __attribute__((aligned(16))) __bf16 Bs[2][64 * 64];

  int tid = threadIdx.x;
  int lane = tid & 63;
  int wr = tid >> 6;
  int l15 = lane & 15, lhi = lane >> 4;

  int rowA = tid >> 3, kc8 = (tid & 7) * 8;
  const __bf16* ap0 = Ap + (size_t)(m0 + rowA) * Kd + kc8;

  int kb = (tid >> 4) * 4;
  int cB = (tid & 15) * 4;
  const float* bp0 = Bp + (size_t)kb * Hn + n0 + cB;

  f32x4 zero = {0.f, 0.f, 0.f, 0.f};
  f32x4 acc[2][4];
#pragma unroll
  for (int i = 0; i < 2; ++i)
#pragma unroll
    for (int j = 0; j < 4; ++j) acc[i][j] = zero;

  bf16x8 qa[4];
  float4 qb[4];

#define LOADS2(K0)                                                          \
  {                                                                         \
    _Pragma("unroll") for (int it = 0; it < 4; ++it)                        \
      qa[it] = *(const bf16x8*)(ap0 + (size_t)(32 * it) * Kd + (K0));       \
    _Pragma("unroll") for (int r = 0; r < 4; ++r)                           \
      qb[r] = *(const float4*)(bp0 + (size_t)((K0) + r) * Hn);              \
  }

#define WRITE2(P)                                                           \
  {                                                                         \
    _Pragma("unroll") for (int it = 0; it < 4; ++it)                        \
      *(bf16x8*)((char*)As[P] + swz(rowA + 32 * it, kc8 * 2)) = qa[it];     \
    _Pragma("unroll") for (int j = 0; j < 4; ++j) {                         \
      bf16x4 cv;                                                            \
      _Pragma("unroll") for (int r = 0; r < 4; ++r)                         \
        cv[r] = (__bf16)(((const float*)&qb[r])[j]);                        \
      *(bf16x4*)((char*)Bs[P] + swz(cB + j, kb * 2)) = cv;                  \
    }                                                                       \
  }

#define MFMA2(P)                                                            \
  _Pragma("unroll") for (int kk = 0; kk < 2; ++kk) {                        \
    int kbyte = kk * 64 + 16 * lhi;                                         \
    bf16x8 af0 = *(const bf16x8*)((char*)As[P] + swz(wr * 32 + l15, kbyte));       \
    bf16x8 af1 = *(const bf16x8*)((char*)As[P] + swz(wr * 32 + 16 + l15, kbyte));  \
    _Pragma("unroll") for (int n = 0; n < 4; ++n) {                         \
      bf16x8 bfr = *(const bf16x8*)((char*)Bs[P] + swz(n * 16 + l15, kbyte));      \
      acc[0][n] = __builtin_amdgcn_mfma_f32_16x16x32_bf16(af0, bfr, acc[0][n], 0, 0, 0); \
      acc[1][n] = __builtin_amdgcn_mfma_f32_16x16x32_bf16(af1, bfr, acc[1][n], 0, 0, 0); \
    }                                                                       \
  }

  int nt = Kd >> 6;
  LOADS2(0);
  WRITE2(0);
  LOADS2(64);
  BAR();
  for (int t = 0; t < nt; ++t) {
    int p = t & 1;
    __builtin_amdgcn_s_setprio(1);
    MFMA2(p);
    __builtin_amdgcn_s_setprio(0);
    if (t + 1 < nt) {
      WRITE2(p ^ 1);
      if (t + 2 < nt) LOADS2((t + 2) << 6);
    }
    BAR();
  }
#undef LOADS2
#undef WRITE2
#undef MFMA2

  if (dstF) {
#pragma unroll
    for (int m = 0; m < 2; ++m)
#pragma unroll
      for (int n = 0; n < 4; ++n)
#pragma unroll
        for (int r = 0; r < 4; ++r) {
          int lrow = wr * 32 + m * 16 + lhi * 4 + r;
          int col = n0 + n * 16 + l15;
          dstF[(size_t)(m0 + lrow) * Hn + col] = acc[m][n][r];
        }
  } else {
#pragma unroll
    for (int m = 0; m < 2; ++m)
#pragma unroll
      for (int n = 0; n < 4; ++n)
#pragma unroll
        for (int r = 0; r < 4; ++r) {
          int lrow = wr * 32 + m * 16 + lhi * 4 + r;
          int col = n0 + n * 16 + l15;
          dstB[(size_t)(m0 + lrow) * Hn + col] = (__bf16)acc[m][n][r];
        }
  }
}

// ---------------- combine: out[t] = shared_out[t] + sum_k w_k * y[e_k, pos_k] ----------------
__global__ void combine_kernel(const int* __restrict__ ids, const float* __restrict__ tw,
                               const int* __restrict__ ppos, const __bf16* __restrict__ y,
                               float* __restrict__ out) {
  int t = blockIdx.x;
  int c0 = threadIdx.x * 8;
  float* orow = out + (size_t)t * Hn + c0;
  float4 a0 = *(const float4*)orow;
  float4 a1 = *(const float4*)(orow + 4);
#pragma unroll
  for (int k = 0; k < Kn; ++k) {
    int f = t * Kn + k;
    int p = ppos[f];
    if (p < 0) continue;
    int e = ids[f];
    float w = tw[f];
    bf16x8 bv = *(const bf16x8*)(y + ((size_t)e * Cn + p) * Hn + c0);
    a0.x += w * (float)bv[0]; a0.y += w * (float)bv[1];
    a0.z += w * (float)bv[2]; a0.w += w * (float)bv[3];
    a1.x += w * (float)bv[4]; a1.y += w * (float)bv[5];
    a1.z += w * (float)bv[6]; a1.w += w * (float)bv[7];
  }
  *(float4*)orow = a0;
  *(float4*)(orow + 4) = a1;
}

extern "C" void kernel_launch(void* const* d_in, const int* in_sizes, int n_in,
                              void* d_out, int out_size, void* d_ws, size_t ws_size,
                              hipStream_t stream) {
  (void)in_sizes; (void)n_in; (void)out_size; (void)ws_size;
  const float* x   = (const float*)d_in[0];
  const float* gw  = (const float*)d_in[1];
  const float* gb  = (const float*)d_in[2];
  const float* w13 = (const float*)d_in[3];
  const float* w2  = (const float*)d_in[4];
  const float* sgu = (const float*)d_in[5];
  const float* sdn = (const float*)d_in[6];
  float* out = (float*)d_out;

  char* ws = (char*)d_ws;
  size_t off = 0;
  int* ids   = (int*)(ws + off);   off += (size_t)Tn * Kn * 4;
  float* tw  = (float*)(ws + off); off += (size_t)Tn * Kn * 4;
  int* ppos  = (int*)(ws + off);   off += (size_t)Tn * Kn * 4;
  int* etok  = (int*)(ws + off);   off += (size_t)En * Cn * 4;
  int* ecnt  = (int*)(ws + off);   off += 256;
  __bf16* xbf  = (__bf16*)(ws + off); off += (size_t)Tn * Hn * 2;
  __bf16* hmid = (__bf16*)(ws + off); off += (size_t)En * Cn * In * 2;
  __bf16* smid = (__bf16*)(ws + off); off += (size_t)Tn * Sn * 2;
  __bf16* y    = (__bf16*)(ws + off); off += (size_t)En * Cn * Hn * 2;

  xcvt_kernel<<<Tn * Hn / (256 * 8), 256, 0, stream>>>(x, xbf);
  router_kernel<<<Tn, 64, 0, stream>>>(x, gw, gb, ids, tw);
  dispatch_kernel<<<En, 256, 0, stream>>>(ids, etok, ppos, ecnt);

  // gemm1: 256 shared + 2048 expert blocks (mseg-adjacent pairs, XCD-decomposed)
  gemm1_fused<<<dim3(256 + 2048), 512, 0, stream>>>(xbf, etok, ecnt, w13, sgu, hmid, smid);
  // gemm2: 256 shared (-> out fp32) + 4096 expert (-> y bf16), no atomics
  gemm2_fused<<<dim3(256 + 4096), 256, 0, stream>>>(hmid, smid, w2, sdn, ecnt, y, out);
  // combine: weighted gather of y + shared out
  combine_kernel<<<Tn, 256, 0, stream>>>(ids, tw, ppos, y, out);
}

// Round 11
// 582.405 us; speedup vs baseline: 1.1462x; 1.1054x over previous
//
#include <hip/hip_runtime.h>
#include <hip/hip_bf16.h>
#include <math.h>

#define Tn 1024
#define Hn 2048
#define En 64
#define Kn 6
#define In 1024
#define Gn 8
#define TGn 3
#define Cn 256
#define Sn 2048
#define RSF 2.5

typedef __bf16 bf16x8 __attribute__((ext_vector_type(8)));
typedef __bf16 bf16x4 __attribute__((ext_vector_type(4)));
typedef float f32x4 __attribute__((ext_vector_type(4)));

// swizzled byte offset within a [rows][64 bf16] (128B-row) LDS tile.
__device__ __forceinline__ int swz(int row, int kbyte) {
  return row * 128 + (kbyte ^ ((((row >> 2) ^ row) & 7) << 4));
}

// one barrier per K-step: make LDS writes visible, never drain vmcnt.
#define BAR()                                                  \
  do {                                                         \
    asm volatile("s_waitcnt lgkmcnt(0)" ::: "memory");         \
    __builtin_amdgcn_sched_barrier(0);                         \
    __builtin_amdgcn_s_barrier();                              \
    __builtin_amdgcn_sched_barrier(0);                         \
  } while (0)

// ---------------- router: sigmoid(x @ gate_w^T) fp64 + grouped top-k + x->bf16 ----------------
__global__ void router_kernel(const float* __restrict__ x, const float* __restrict__ gw,
                              const float* __restrict__ gb, int* __restrict__ ids,
                              float* __restrict__ tw, __bf16* __restrict__ xbf) {
  __shared__ float xs[Hn];
  __shared__ double sds[En];
  __shared__ double gs[Gn];
  int t = blockIdx.x;
  for (int i = threadIdx.x * 4; i < Hn; i += 64 * 4)
    *(float4*)(xs + i) = *(const float4*)(x + (size_t)t * Hn + i);
  __syncthreads();
  // fused x -> bf16 conversion (xs already staged)
  for (int i = threadIdx.x * 8; i < Hn; i += 64 * 8) {
    bf16x8 h;
#pragma unroll
    for (int j = 0; j < 8; ++j) h[j] = (__bf16)xs[i + j];
    *(bf16x8*)(xbf + (size_t)t * Hn + i) = h;
  }
  int e = threadIdx.x;
  const float* w = gw + (size_t)e * Hn;
  double a0 = 0.0, a1 = 0.0, a2 = 0.0, a3 = 0.0;
  for (int i = 0; i < Hn; i += 4) {
    float4 b = *(const float4*)(w + i);
    a0 += (double)xs[i] * b.x;
    a1 += (double)xs[i + 1] * b.y;
    a2 += (double)xs[i + 2] * b.z;
    a3 += (double)xs[i + 3] * b.w;
  }
  double acc = (a0 + a1) + (a2 + a3);
  sds[e] = 1.0 / (1.0 + exp(-acc));
  __syncthreads();
  if (e < Gn) {
    double m1 = -1e300, m2 = -1e300;
    for (int j = 0; j < 8; ++j) {
      double v = sds[e * 8 + j] + (double)gb[e * 8 + j];
      if (v > m1) { m2 = m1; m1 = v; } else if (v > m2) m2 = v;
    }
    gs[e] = m1 + m2;
  }
  __syncthreads();
  if (e == 0) {
    unsigned gsel = 0;
    for (int it = 0; it < TGn; ++it) {
      double best = -1e300; int bi = 0;
      for (int g = 0; g < Gn; ++g)
        if (!((gsel >> g) & 1) && gs[g] > best) { best = gs[g]; bi = g; }
      gsel |= 1u << bi;
    }
    unsigned long long taken = 0ull;
    int sel[Kn]; double wv[Kn]; double wsum = 0.0;
    for (int k = 0; k < Kn; ++k) {
      double best = -1e300; int bi = 0;
      for (int ee = 0; ee < En; ++ee) {
        if (!((gsel >> (ee >> 3)) & 1)) continue;
        if ((taken >> ee) & 1) continue;
        double v = sds[ee] + (double)gb[ee];
        if (v > best) { best = v; bi = ee; }
      }
      taken |= 1ull << bi;
      sel[k] = bi;
      wv[k] = sds[bi];
      wsum += wv[k];
    }
    double inv = RSF / (wsum + 1e-20);
    for (int k = 0; k < Kn; ++k) {
      ids[t * Kn + k] = sel[k];
      tw[t * Kn + k] = (float)(wv[k] * inv);
    }
  }
}

// ---------------- dispatch: ballot-rank scan, cumsum position semantics ----------------
__global__ void dispatch_kernel(const int* __restrict__ ids, int* __restrict__ etok,
                                int* __restrict__ ppos, int* __restrict__ ecnt) {
  int e = blockIdx.x;
  int tid = threadIdx.x;
  int lane = tid & 63, wv = tid >> 6;
  __shared__ int wcnt[4];
  int base = 0;
  for (int c = 0; c < Tn * Kn; c += 256) {
    int f = c + tid;
    bool p = (ids[f] == e);
    unsigned long long m = __ballot(p);
    int rank = __popcll(m & ((1ull << lane) - 1ull));
    if (lane == 0) wcnt[wv] = __popcll(m);
    __syncthreads();
    int woff = 0;
    for (int w = 0; w < wv; ++w) woff += wcnt[w];
    int tot = wcnt[0] + wcnt[1] + wcnt[2] + wcnt[3];
    if (p) {
      int pos = base + woff + rank;
      if (pos < Cn) { etok[e * Cn + pos] = f / Kn; ppos[f] = pos; }
      else ppos[f] = -1;
    }
    base += tot;
    __syncthreads();
  }
  int cc = base < Cn ? base : Cn;
  for (int cpos = cc + tid; cpos < Cn; cpos += 256) etok[e * Cn + cpos] = -1;
  if (tid == 0) ecnt[e] = cc;
}

// ---------------- GEMM1 fused (expert + shared): xbf @ W13 / sgu, SiLU*mul, bf16 out ----
// 512 threads (8 waves x 16-row tiles), BM=128, BN=64(g)+64(u), BK=64, dbuf LDS.
__global__ __launch_bounds__(512, 4)
void gemm1_fused(const __bf16* __restrict__ A, const int* __restrict__ etok,
                 const int* __restrict__ ecnt, const float* __restrict__ w13,
                 const float* __restrict__ sgu, __bf16* __restrict__ hmid,
                 __bf16* __restrict__ smid) {
  int hw = blockIdx.x;
  int m0, n0, Nhalf, mlim;
  const int* rows = nullptr;
  const float* Bp;
  __bf16* Op;
  if (hw < 256) {                      // shared: 8 msegs x 32 ntiles
    m0 = (hw >> 5) * 128; n0 = (hw & 31) * 64;
    Nhalf = Sn; Bp = sgu; Op = smid; mlim = 128;
  } else {                             // expert: 8 xcd x 8 e x (2 mseg x 16 ntile)
    int ex = hw - 256;
    int xcd = ex & 7, slot = ex >> 3;
    int e = xcd * 8 + (slot >> 5);
    int within = slot & 31;
    m0 = (within >> 4) * 128; n0 = (within & 15) * 64;
    int cnt = ecnt[e];
    if (cnt <= m0) return;
    mlim = cnt - m0; if (mlim > 128) mlim = 128;   // valid rows in this block
    Nhalf = In; Bp = w13 + (size_t)e * Hn * 2 * In;
    Op = hmid + (size_t)e * Cn * In; rows = etok + e * Cn;
  }

  __shared__ __attribute__((aligned(16))) __bf16 As[2][128 * 64];
  __shared__ __attribute__((aligned(16))) __bf16 Bg[2][64 * 64];
  __shared__ __attribute__((aligned(16))) __bf16 Bu[2][64 * 64];
  __shared__ int rowix[128];

  int tid = threadIdx.x;
  if (tid < 128) {
    int r;
    if (rows) { int v = rows[m0 + tid]; r = v < 0 ? 0 : v; }
    else r = m0 + tid;
    rowix[tid] = r;
  }
  __syncthreads();

  int lane = tid & 63;
  int wv = tid >> 6;                 // 0..7, wave owns rows [16*wv, 16*wv+16)
  int l15 = lane & 15, lhi = lane >> 4;

  int rowA = tid >> 3, kc8 = (tid & 7) * 8, kcB = (tid & 7) * 16;
  const __bf16* arow0 = A + (size_t)rowix[rowA] * Hn + kc8;
  const __bf16* arow1 = A + (size_t)rowix[rowA + 64] * Hn + kc8;

  int bt = tid & 255;
  int kb = (bt >> 4) * 4;
  int cB = (bt & 15) * 4;
  size_t ldb = (size_t)2 * Nhalf;
  const float* bsrc = Bp + (size_t)kb * ldb + n0 + cB + (tid >= 256 ? Nhalf : 0);

  f32x4 zero = {0.f, 0.f, 0.f, 0.f};
  f32x4 accg[4], accu[4];
#pragma unroll
  for (int j = 0; j < 4; ++j) { accg[j] = zero; accu[j] = zero; }

  bf16x8 qa0, qa1;
  float4 qb[4];

#define LOADS1(K0)                                                         \
  {                                                                        \
    qa0 = *(const bf16x8*)(arow0 + (K0));                                  \
    qa1 = *(const bf16x8*)(arow1 + (K0));                                  \
    _Pragma("unroll") for (int r = 0; r < 4; ++r)                          \
      qb[r] = *(const float4*)(bsrc + (size_t)((K0) + r) * ldb);           \
  }

#define WRITE1(P)                                                          \
  {                                                                        \
    *(bf16x8*)((char*)As[P] + swz(rowA, kcB)) = qa0;                       \
    *(bf16x8*)((char*)As[P] + swz(rowA + 64, kcB)) = qa1;                  \
    __bf16* BtP = (tid >= 256) ? Bu[P] : Bg[P];                            \
    _Pragma("unroll") for (int j = 0; j < 4; ++j) {                        \
      bf16x4 cv;                                                           \
      _Pragma("unroll") for (int r = 0; r < 4; ++r)                        \
        cv[r] = (__bf16)(((const float*)&qb[r])[j]);                       \
      *(bf16x4*)((char*)BtP + swz(cB + j, kb * 2)) = cv;                   \
    }                                                                      \
  }

#define MFMA1(P)                                                           \
  _Pragma("unroll") for (int kk = 0; kk < 2; ++kk) {                       \
    int kbyte = kk * 64 + 16 * lhi;                                        \
    bf16x8 af = *(const bf16x8*)((char*)As[P] + swz(wv * 16 + l15, kbyte));\
    _Pragma("unroll") for (int n = 0; n < 4; ++n) {                        \
      bf16x8 fg = *(const bf16x8*)((char*)Bg[P] + swz(n * 16 + l15, kbyte)); \
      accg[n] = __builtin_amdgcn_mfma_f32_16x16x32_bf16(af, fg, accg[n], 0, 0, 0); \
      bf16x8 fu = *(const bf16x8*)((char*)Bu[P] + swz(n * 16 + l15, kbyte)); \
      accu[n] = __builtin_amdgcn_mfma_f32_16x16x32_bf16(af, fu, accu[n], 0, 0, 0); \
    }                                                                      \
  }

  const int nt = Hn >> 6;   // 32
  LOADS1(0);
  WRITE1(0);
  LOADS1(64);
  BAR();
  for (int t = 0; t < nt; ++t) {
    int p = t & 1;
    __builtin_amdgcn_s_setprio(1);
    MFMA1(p);
    __builtin_amdgcn_s_setprio(0);
    if (t + 1 < nt) {
      WRITE1(p ^ 1);
      if (t + 2 < nt) LOADS1((t + 2) << 6);
    }
    BAR();
  }
#undef LOADS1
#undef WRITE1
#undef MFMA1

#pragma unroll
  for (int n = 0; n < 4; ++n)
#pragma unroll
    for (int r = 0; r < 4; ++r) {
      int lrow = wv * 16 + lhi * 4 + r;
      if (lrow >= mlim) continue;           // skip dead capacity rows
      int col = n0 + n * 16 + l15;
      float g = accg[n][r], u = accu[n][r];
      float v = g / (1.f + __expf(-g)) * u;
      Op[(size_t)(m0 + lrow) * Nhalf + col] = (__bf16)v;
    }
}

// ---------------- GEMM2 fused (expert + shared): plain stores, NO atomics ----------------
// 256 threads (4 waves x 32-row tiles), BM=128, BN=64, dbuf pipeline.
__global__ __launch_bounds__(256, 4)
void gemm2_fused(const __bf16* __restrict__ hmid, const __bf16* __restrict__ smid,
                 const float* __restrict__ w2, const float* __restrict__ sdn,
                 const int* __restrict__ ecnt, __bf16* __restrict__ y,
                 float* __restrict__ out) {
  int hw = blockIdx.x;
  int m0, n0, Kd, mlim;
  const __bf16* Ap;
  const float* Bp;
  float* dstF = nullptr;
  __bf16* dstB = nullptr;
  if (hw < 256) {                      // shared: 8 msegs x 32 ntiles
    m0 = (hw >> 5) * 128; n0 = (hw & 31) * 64;
    Kd = Sn; Ap = smid; Bp = sdn; dstF = out; mlim = 128;
  } else {                             // expert: 8 xcd x 8 e x (2 mseg x 32 ntile)
    int ex = hw - 256;
    int xcd = ex & 7, slot = ex >> 3;
    int e = xcd * 8 + (slot >> 6);
    int within = slot & 63;
    m0 = (within >> 5) * 128; n0 = (within & 31) * 64;
    int cnt = ecnt[e];
    if (cnt <= m0) return;
    mlim = cnt - m0; if (mlim > 128) mlim = 128;
    Kd = In; Ap = hmid + (size_t)e * Cn * In;
    Bp = w2 + (size_t)e * In * Hn; dstB = y + (size_t)e * Cn * Hn;
  }

  __shared__ __attribute__((aligned(16))) __bf16 As[2][128 * 64];
  __shared__ __attribute__((aligned(16))) __bf16 Bs[2][64 * 64];

  int tid = threadIdx.x;
  int lane = tid & 63;
  int wr = tid >> 6;
  int l15 = lane & 15, lhi = lane >> 4;

  int rowA = tid >> 3, kc8 = (tid & 7) * 8;
  const __bf16* ap0 = Ap + (size_t)(m0 + rowA) * Kd + kc8;

  int kb = (tid >> 4) * 4;
  int cB = (tid & 15) * 4;
  const float* bp0 = Bp + (size_t)kb * Hn + n0 + cB;

  f32x4 zero = {0.f, 0.f, 0.f, 0.f};
  f32x4 acc[2][4];
#pragma unroll
  for (int i = 0; i < 2; ++i)
#pragma unroll
    for (int j = 0; j < 4; ++j) acc[i][j] = zero;

  bf16x8 qa[4];
  float4 qb[4];

#define LOADS2(K0)                                                          \
  {                                                                         \
    _Pragma("unroll") for (int it = 0; it < 4; ++it)                        \
      qa[it] = *(const bf16x8*)(ap0 + (size_t)(32 * it) * Kd + (K0));       \
    _Pragma("unroll") for (int r = 0; r < 4; ++r)                           \
      qb[r] = *(const float4*)(bp0 + (size_t)((K0) + r) * Hn);              \
  }

#define WRITE2(P)                                                           \
  {                                                                         \
    _Pragma("unroll") for (int it = 0; it < 4; ++it)                        \
      *(bf16x8*)((char*)As[P] + swz(rowA + 32 * it, kc8 * 2)) = qa[it];     \
    _Pragma("unroll") for (int j = 0; j < 4; ++j) {                         \
      bf16x4 cv;                                                            \
      _Pragma("unroll") for (int r = 0; r < 4; ++r)                         \
        cv[r] = (__bf16)(((const float*)&qb[r])[j]);                        \
      *(bf16x4*)((char*)Bs[P] + swz(cB + j, kb * 2)) = cv;                  \
    }                                                                       \
  }

#define MFMA2(P)                                                            \
  _Pragma("unroll") for (int kk = 0; kk < 2; ++kk) {                        \
    int kbyte = kk * 64 + 16 * lhi;                                         \
    bf16x8 af0 = *(const bf16x8*)((char*)As[P] + swz(wr * 32 + l15, kbyte));       \
    bf16x8 af1 = *(const bf16x8*)((char*)As[P] + swz(wr * 32 + 16 + l15, kbyte));  \
    _Pragma("unroll") for (int n = 0; n < 4; ++n) {                         \
      bf16x8 bfr = *(const bf16x8*)((char*)Bs[P] + swz(n * 16 + l15, kbyte));      \
      acc[0][n] = __builtin_amdgcn_mfma_f32_16x16x32_bf16(af0, bfr, acc[0][n], 0, 0, 0); \
      acc[1][n] = __builtin_amdgcn_mfma_f32_16x16x32_bf16(af1, bfr, acc[1][n], 0, 0, 0); \
    }                                                                       \
  }

  int nt = Kd >> 6;
  LOADS2(0);
  WRITE2(0);
  LOADS2(64);
  BAR();
  for (int t = 0; t < nt; ++t) {
    int p = t & 1;
    __builtin_amdgcn_s_setprio(1);
    MFMA2(p);
    __builtin_amdgcn_s_setprio(0);
    if (t + 1 < nt) {
      WRITE2(p ^ 1);
      if (t + 2 < nt) LOADS2((t + 2) << 6);
    }
    BAR();
  }
#undef LOADS2
#undef WRITE2
#undef MFMA2

  if (dstF) {
#pragma unroll
    for (int m = 0; m < 2; ++m)
#pragma unroll
      for (int n = 0; n < 4; ++n)
#pragma unroll
        for (int r = 0; r < 4; ++r) {
          int lrow = wr * 32 + m * 16 + lhi * 4 + r;
          int col = n0 + n * 16 + l15;
          dstF[(size_t)(m0 + lrow) * Hn + col] = acc[m][n][r];
        }
  } else {
#pragma unroll
    for (int m = 0; m < 2; ++m)
#pragma unroll
      for (int n = 0; n < 4; ++n)
#pragma unroll
        for (int r = 0; r < 4; ++r) {
          int lrow = wr * 32 + m * 16 + lhi * 4 + r;
          if (lrow >= mlim) continue;      // skip dead capacity rows
          int col = n0 + n * 16 + l15;
          dstB[(size_t)(m0 + lrow) * Hn + col] = (__bf16)acc[m][n][r];
        }
  }
}

// ---------------- combine: out[t] = shared_out[t] + sum_k w_k * y[e_k, pos_k] ----------------
__global__ void combine_kernel(const int* __restrict__ ids, const float* __restrict__ tw,
                               const int* __restrict__ ppos, const __bf16* __restrict__ y,
                               float* __restrict__ out) {
  int t = blockIdx.x;
  int c0 = threadIdx.x * 8;
  float* orow = out + (size_t)t * Hn + c0;
  float4 a0 = *(const float4*)orow;
  float4 a1 = *(const float4*)(orow + 4);
#pragma unroll
  for (int k = 0; k < Kn; ++k) {
    int f = t * Kn + k;
    int p = ppos[f];
    if (p < 0) continue;
    int e = ids[f];
    float w = tw[f];
    bf16x8 bv = *(const bf16x8*)(y + ((size_t)e * Cn + p) * Hn + c0);
    a0.x += w * (float)bv[0]; a0.y += w * (float)bv[1];
    a0.z += w * (float)bv[2]; a0.w += w * (float)bv[3];
    a1.x += w * (float)bv[4]; a1.y += w * (float)bv[5];
    a1.z += w * (float)bv[6]; a1.w += w * (float)bv[7];
  }
  *(float4*)orow = a0;
  *(float4*)(orow + 4) = a1;
}

extern "C" void kernel_launch(void* const* d_in, const int* in_sizes, int n_in,
                              void* d_out, int out_size, void* d_ws, size_t ws_size,
                              hipStream_t stream) {
  (void)in_sizes; (void)n_in; (void)out_size; (void)ws_size;
  const float* x   = (const float*)d_in[0];
  const float* gw  = (const float*)d_in[1];
  const float* gb  = (const float*)d_in[2];
  const float* w13 = (const float*)d_in[3];
  const float* w2  = (const float*)d_in[4];
  const float* sgu = (const float*)d_in[5];
  const float* sdn = (const float*)d_in[6];
  float* out = (float*)d_out;

  char* ws = (char*)d_ws;
  size_t off = 0;
  int* ids   = (int*)(ws + off);   off += (size_t)Tn * Kn * 4;
  float* tw  = (float*)(ws + off); off += (size_t)Tn * Kn * 4;
  int* ppos  = (int*)(ws + off);   off += (size_t)Tn * Kn * 4;
  int* etok  = (int*)(ws + off);   off += (size_t)En * Cn * 4;
  int* ecnt  = (int*)(ws + off);   off += 256;
  __bf16* xbf  = (__bf16*)(ws + off); off += (size_t)Tn * Hn * 2;
  __bf16* hmid = (__bf16*)(ws + off); off += (size_t)En * Cn * In * 2;
  __bf16* smid = (__bf16*)(ws + off); off += (size_t)Tn * Sn * 2;
  __bf16* y    = (__bf16*)(ws + off); off += (size_t)En * Cn * Hn * 2;

  router_kernel<<<Tn, 64, 0, stream>>>(x, gw, gb, ids, tw, xbf);
  dispatch_kernel<<<En, 256, 0, stream>>>(ids, etok, ppos, ecnt);

  // gemm1: 256 shared + 2048 expert blocks (XCD-decomposed)
  gemm1_fused<<<dim3(256 + 2048), 512, 0, stream>>>(xbf, etok, ecnt, w13, sgu, hmid, smid);
  // gemm2: 256 shared (-> out fp32) + 4096 expert (-> y bf16), no atomics
  gemm2_fused<<<dim3(256 + 4096), 256, 0, stream>>>(hmid, smid, w2, sdn, ecnt, y, out);
  // combine: weighted gather of y + shared out
  combine_kernel<<<Tn, 256, 0, stream>>>(ids, tw, ppos, y, out);
}

// Round 12
// 578.382 us; speedup vs baseline: 1.1542x; 1.0070x over previous
//
#include <hip/hip_runtime.h>
#include <hip/hip_bf16.h>
#include <math.h>

#define Tn 1024
#define Hn 2048
#define En 64
#define Kn 6
#define In 1024
#define Gn 8
#define TGn 3
#define Cn 256
#define Sn 2048
#define RSF 2.5

typedef __bf16 bf16x8 __attribute__((ext_vector_type(8)));
typedef __bf16 bf16x4 __attribute__((ext_vector_type(4)));
typedef float f32x4 __attribute__((ext_vector_type(4)));

// swizzled byte offset within a [rows][64 bf16] (128B-row) LDS tile.
__device__ __forceinline__ int swz(int row, int kbyte) {
  return row * 128 + (kbyte ^ ((((row >> 2) ^ row) & 7) << 4));
}
// element offset within a 64-elem row that lane's linear 16B slot must fetch
// so that the LINEAR gload_lds write lands data at swizzled positions.
__device__ __forceinline__ int inv_kof(int row, int lane7) {
  return ((lane7 * 16) ^ ((((row >> 2) ^ row) & 7) << 4)) >> 1;
}

__device__ __forceinline__ void gload16(const void* g, void* l) {
  typedef __attribute__((address_space(1))) const void gvoid;
  typedef __attribute__((address_space(3))) void lvoid;
  __builtin_amdgcn_global_load_lds((gvoid*)g, (lvoid*)l, 16, 0, 0);
}

// ---------------- router: sigmoid(x @ gate_w^T) fp64 + grouped top-k + x->bf16 ----------------
__global__ void router_kernel(const float* __restrict__ x, const float* __restrict__ gw,
                              const float* __restrict__ gb, int* __restrict__ ids,
                              float* __restrict__ tw, __bf16* __restrict__ xbf) {
  __shared__ float xs[Hn];
  __shared__ double sds[En];
  __shared__ double gs[Gn];
  int t = blockIdx.x;
  for (int i = threadIdx.x * 4; i < Hn; i += 64 * 4)
    *(float4*)(xs + i) = *(const float4*)(x + (size_t)t * Hn + i);
  __syncthreads();
  for (int i = threadIdx.x * 8; i < Hn; i += 64 * 8) {
    bf16x8 h;
#pragma unroll
    for (int j = 0; j < 8; ++j) h[j] = (__bf16)xs[i + j];
    *(bf16x8*)(xbf + (size_t)t * Hn + i) = h;
  }
  int e = threadIdx.x;
  const float* w = gw + (size_t)e * Hn;
  double a0 = 0.0, a1 = 0.0, a2 = 0.0, a3 = 0.0;
  for (int i = 0; i < Hn; i += 4) {
    float4 b = *(const float4*)(w + i);
    a0 += (double)xs[i] * b.x;
    a1 += (double)xs[i + 1] * b.y;
    a2 += (double)xs[i + 2] * b.z;
    a3 += (double)xs[i + 3] * b.w;
  }
  double acc = (a0 + a1) + (a2 + a3);
  sds[e] = 1.0 / (1.0 + exp(-acc));
  __syncthreads();
  if (e < Gn) {
    double m1 = -1e300, m2 = -1e300;
    for (int j = 0; j < 8; ++j) {
      double v = sds[e * 8 + j] + (double)gb[e * 8 + j];
      if (v > m1) { m2 = m1; m1 = v; } else if (v > m2) m2 = v;
    }
    gs[e] = m1 + m2;
  }
  __syncthreads();
  if (e == 0) {
    unsigned gsel = 0;
    for (int it = 0; it < TGn; ++it) {
      double best = -1e300; int bi = 0;
      for (int g = 0; g < Gn; ++g)
        if (!((gsel >> g) & 1) && gs[g] > best) { best = gs[g]; bi = g; }
      gsel |= 1u << bi;
    }
    unsigned long long taken = 0ull;
    int sel[Kn]; double wv[Kn]; double wsum = 0.0;
    for (int k = 0; k < Kn; ++k) {
      double best = -1e300; int bi = 0;
      for (int ee = 0; ee < En; ++ee) {
        if (!((gsel >> (ee >> 3)) & 1)) continue;
        if ((taken >> ee) & 1) continue;
        double v = sds[ee] + (double)gb[ee];
        if (v > best) { best = v; bi = ee; }
      }
      taken |= 1ull << bi;
      sel[k] = bi;
      wv[k] = sds[bi];
      wsum += wv[k];
    }
    double inv = RSF / (wsum + 1e-20);
    for (int k = 0; k < Kn; ++k) {
      ids[t * Kn + k] = sel[k];
      tw[t * Kn + k] = (float)(wv[k] * inv);
    }
  }
}

// ---------------- dispatch: ballot-rank scan, cumsum position semantics ----------------
__global__ void dispatch_kernel(const int* __restrict__ ids, int* __restrict__ etok,
                                int* __restrict__ ppos, int* __restrict__ ecnt) {
  int e = blockIdx.x;
  int tid = threadIdx.x;
  int lane = tid & 63, wv = tid >> 6;
  __shared__ int wcnt[4];
  int base = 0;
  for (int c = 0; c < Tn * Kn; c += 256) {
    int f = c + tid;
    bool p = (ids[f] == e);
    unsigned long long m = __ballot(p);
    int rank = __popcll(m & ((1ull << lane) - 1ull));
    if (lane == 0) wcnt[wv] = __popcll(m);
    __syncthreads();
    int woff = 0;
    for (int w = 0; w < wv; ++w) woff += wcnt[w];
    int tot = wcnt[0] + wcnt[1] + wcnt[2] + wcnt[3];
    if (p) {
      int pos = base + woff + rank;
      if (pos < Cn) { etok[e * Cn + pos] = f / Kn; ppos[f] = pos; }
      else ppos[f] = -1;
    }
    base += tot;
    __syncthreads();
  }
  int cc = base < Cn ? base : Cn;
  for (int cpos = cc + tid; cpos < Cn; cpos += 256) etok[e * Cn + cpos] = -1;
  if (tid == 0) ecnt[e] = cc;
}

// ---------------- GEMM1 fused: A via global_load_lds (pre-swizzled source), B reg-staged ----
// 512 threads (8 waves x 16-row tiles), BM=128, BN=64(g)+64(u), BK=64, dbuf LDS.
__global__ __launch_bounds__(512, 4)
void gemm1_fused(const __bf16* __restrict__ A, const int* __restrict__ etok,
                 const int* __restrict__ ecnt, const float* __restrict__ w13,
                 const float* __restrict__ sgu, __bf16* __restrict__ hmid,
                 __bf16* __restrict__ smid) {
  int hw = blockIdx.x;
  int m0, n0, Nhalf, mlim;
  const int* rows = nullptr;
  const float* Bp;
  __bf16* Op;
  if (hw < 256) {                      // shared: 8 msegs x 32 ntiles
    m0 = (hw >> 5) * 128; n0 = (hw & 31) * 64;
    Nhalf = Sn; Bp = sgu; Op = smid; mlim = 128;
  } else {                             // expert: 8 xcd x 8 e x (2 mseg x 16 ntile)
    int ex = hw - 256;
    int xcd = ex & 7, slot = ex >> 3;
    int e = xcd * 8 + (slot >> 5);
    int within = slot & 31;
    m0 = (within >> 4) * 128; n0 = (within & 15) * 64;
    int cnt = ecnt[e];
    if (cnt <= m0) return;
    mlim = cnt - m0; if (mlim > 128) mlim = 128;
    Nhalf = In; Bp = w13 + (size_t)e * Hn * 2 * In;
    Op = hmid + (size_t)e * Cn * In; rows = etok + e * Cn;
  }

  __shared__ __attribute__((aligned(16))) __bf16 As[2][128 * 64];
  __shared__ __attribute__((aligned(16))) __bf16 Bg[2][64 * 64];
  __shared__ __attribute__((aligned(16))) __bf16 Bu[2][64 * 64];
  __shared__ int rowix[128];

  int tid = threadIdx.x;
  if (tid < 128) {
    int r;
    if (rows) { int v = rows[m0 + tid]; r = v < 0 ? 0 : v; }
    else r = m0 + tid;
    rowix[tid] = r;
  }
  __syncthreads();

  int lane = tid & 63;
  int wv = tid >> 6;                 // 0..7, wave owns rows [16*wv, 16*wv+16)
  int l15 = lane & 15, lhi = lane >> 4;

  // A gload geometry: wave wv, issue i (0,1), lane l -> LDS byte wv*2048+i*1024+l*16
  int ar0 = wv * 16 + (lane >> 3);   // block-local row, issue 0
  int ar1 = ar0 + 8;                 // issue 1
  const __bf16* ga0 = A + (size_t)rowix[ar0] * Hn + inv_kof(ar0, lane & 7);
  const __bf16* ga1 = A + (size_t)rowix[ar1] * Hn + inv_kof(ar1, lane & 7);

  int bt = tid & 255;
  int kb = (bt >> 4) * 4;
  int cB = (bt & 15) * 4;
  size_t ldb = (size_t)2 * Nhalf;
  const float* bsrc = Bp + (size_t)kb * ldb + n0 + cB + (tid >= 256 ? Nhalf : 0);

  f32x4 zero = {0.f, 0.f, 0.f, 0.f};
  f32x4 accg[4], accu[4];
#pragma unroll
  for (int j = 0; j < 4; ++j) { accg[j] = zero; accu[j] = zero; }

  float4 qb[4];

#define GLOADA1(P, K0)                                                     \
  {                                                                        \
    gload16(ga0 + (K0), (char*)As + (P) * 16384 + wv * 2048);              \
    gload16(ga1 + (K0), (char*)As + (P) * 16384 + wv * 2048 + 1024);       \
  }

#define LOADB1(K0)                                                         \
  { _Pragma("unroll") for (int r = 0; r < 4; ++r)                          \
      qb[r] = *(const float4*)(bsrc + (size_t)((K0) + r) * ldb); }

#define WRITEB1(P)                                                         \
  {                                                                        \
    __bf16* BtP = (tid >= 256) ? Bu[P] : Bg[P];                            \
    _Pragma("unroll") for (int j = 0; j < 4; ++j) {                        \
      bf16x4 cv;                                                           \
      _Pragma("unroll") for (int r = 0; r < 4; ++r)                        \
        cv[r] = (__bf16)(((const float*)&qb[r])[j]);                       \
      *(bf16x4*)((char*)BtP + swz(cB + j, kb * 2)) = cv;                   \
    }                                                                      \
  }

#define MFMA1(P)                                                           \
  _Pragma("unroll") for (int kk = 0; kk < 2; ++kk) {                       \
    int kbyte = kk * 64 + 16 * lhi;                                        \
    bf16x8 af = *(const bf16x8*)((char*)As[P] + swz(wv * 16 + l15, kbyte));\
    _Pragma("unroll") for (int n = 0; n < 4; ++n) {                        \
      bf16x8 fg = *(const bf16x8*)((char*)Bg[P] + swz(n * 16 + l15, kbyte)); \
      accg[n] = __builtin_amdgcn_mfma_f32_16x16x32_bf16(af, fg, accg[n], 0, 0, 0); \
      bf16x8 fu = *(const bf16x8*)((char*)Bu[P] + swz(n * 16 + l15, kbyte)); \
      accu[n] = __builtin_amdgcn_mfma_f32_16x16x32_bf16(af, fu, accu[n], 0, 0, 0); \
    }                                                                      \
  }

  const int nt = Hn >> 6;   // 32
  GLOADA1(0, 0);
  LOADB1(0);
  GLOADA1(1, 64);
  WRITEB1(0);
  LOADB1(64);
  asm volatile("s_waitcnt vmcnt(0) lgkmcnt(0)" ::: "memory");
  __builtin_amdgcn_sched_barrier(0);
  __builtin_amdgcn_s_barrier();
  __builtin_amdgcn_sched_barrier(0);
  for (int t = 0; t < nt; ++t) {
    int p = t & 1;
    __builtin_amdgcn_s_setprio(1);
    MFMA1(p);
    __builtin_amdgcn_s_setprio(0);
    __builtin_amdgcn_sched_barrier(0);
    if (t + 2 < nt) GLOADA1(p, (t + 2) << 6);   // A(t+2) -> As[p] (safe: reads done)
    if (t + 1 < nt) WRITEB1(p ^ 1);             // B(t+1) regs -> LDS
    if (t + 2 < nt) {
      LOADB1((t + 2) << 6);                     // B(t+2) -> regs
      asm volatile("s_waitcnt vmcnt(6) lgkmcnt(0)" ::: "memory");  // drain A(t+1)
    } else {
      asm volatile("s_waitcnt vmcnt(0) lgkmcnt(0)" ::: "memory");
    }
    __builtin_amdgcn_sched_barrier(0);
    __builtin_amdgcn_s_barrier();
    __builtin_amdgcn_sched_barrier(0);
  }
#undef GLOADA1
#undef LOADB1
#undef WRITEB1
#undef MFMA1

#pragma unroll
  for (int n = 0; n < 4; ++n)
#pragma unroll
    for (int r = 0; r < 4; ++r) {
      int lrow = wv * 16 + lhi * 4 + r;
      if (lrow >= mlim) continue;
      int col = n0 + n * 16 + l15;
      float g = accg[n][r], u = accu[n][r];
      float v = g / (1.f + __expf(-g)) * u;
      Op[(size_t)(m0 + lrow) * Nhalf + col] = (__bf16)v;
    }
}

// ---------------- GEMM2 fused: A via global_load_lds, B reg-staged, plain stores ----------
// 256 threads (4 waves x 32-row tiles), BM=128, BN=64, dbuf LDS.
__global__ __launch_bounds__(256, 4)
void gemm2_fused(const __bf16* __restrict__ hmid, const __bf16* __restrict__ smid,
                 const float* __restrict__ w2, const float* __restrict__ sdn,
                 const int* __restrict__ ecnt, __bf16* __restrict__ y,
                 float* __restrict__ out) {
  int hw = blockIdx.x;
  int m0, n0, Kd, mlim;
  const __bf16* Ap;
  const float* Bp;
  float* dstF = nullptr;
  __bf16* dstB = nullptr;
  if (hw < 256) {                      // shared: 8 msegs x 32 ntiles
    m0 = (hw >> 5) * 128; n0 = (hw & 31) * 64;
    Kd = Sn; Ap = smid; Bp = sdn; dstF = out; mlim = 128;
  } else {                             // expert: 8 xcd x 8 e x (2 mseg x 32 ntile)
    int ex = hw - 256;
    int xcd = ex & 7, slot = ex >> 3;
    int e = xcd * 8 + (slot >> 6);
    int within = slot & 63;
    m0 = (within >> 5) * 128; n0 = (within & 31) * 64;
    int cnt = ecnt[e];
    if (cnt <= m0) return;
    mlim = cnt - m0; if (mlim > 128) mlim = 128;
    Kd = In; Ap = hmid + (size_t)e * Cn * In;
    Bp = w2 + (size_t)e * In * Hn; dstB = y + (size_t)e * Cn * Hn;
  }

  __shared__ __attribute__((aligned(16))) __bf16 As[2][128 * 64];
  __shared__ __attribute__((aligned(16))) __bf16 Bs[2][64 * 64];

  int tid = threadIdx.x;
  int lane = tid & 63;
  int wr = tid >> 6;
  int l15 = lane & 15, lhi = lane >> 4;

  // A gload geometry: wave wr covers rows [wr*32, wr*32+32), 4 issues x 1KB
  const __bf16* ga[4];
#pragma unroll
  for (int i = 0; i < 4; ++i) {
    int ar = wr * 32 + i * 8 + (lane >> 3);
    ga[i] = Ap + (size_t)(m0 + ar) * Kd + inv_kof(ar, lane & 7);
  }

  int kb = (tid >> 4) * 4;
  int cB = (tid & 15) * 4;
  const float* bp0 = Bp + (size_t)kb * Hn + n0 + cB;

  f32x4 zero = {0.f, 0.f, 0.f, 0.f};
  f32x4 acc[2][4];
#pragma unroll
  for (int i = 0; i < 2; ++i)
#pragma unroll
    for (int j = 0; j < 4; ++j) acc[i][j] = zero;

  float4 qb[4];

#define GLOADA2(P, K0)                                                      \
  { _Pragma("unroll") for (int i = 0; i < 4; ++i)                           \
      gload16(ga[i] + (K0), (char*)As + (P) * 16384 + wr * 4096 + i * 1024); }

#define LOADB2(K0)                                                          \
  { _Pragma("unroll") for (int r = 0; r < 4; ++r)                           \
      qb[r] = *(const float4*)(bp0 + (size_t)((K0) + r) * Hn); }

#define WRITEB2(P)                                                          \
  { _Pragma("unroll") for (int j = 0; j < 4; ++j) {                         \
      bf16x4 cv;                                                            \
      _Pragma("unroll") for (int r = 0; r < 4; ++r)                         \
        cv[r] = (__bf16)(((const float*)&qb[r])[j]);                        \
      *(bf16x4*)((char*)Bs[P] + swz(cB + j, kb * 2)) = cv;                  \
    } }

#define MFMA2(P)                                                            \
  _Pragma("unroll") for (int kk = 0; kk < 2; ++kk) {                        \
    int kbyte = kk * 64 + 16 * lhi;                                         \
    bf16x8 af0 = *(const bf16x8*)((char*)As[P] + swz(wr * 32 + l15, kbyte));       \
    bf16x8 af1 = *(const bf16x8*)((char*)As[P] + swz(wr * 32 + 16 + l15, kbyte));  \
    _Pragma("unroll") for (int n = 0; n < 4; ++n) {                         \
      bf16x8 bfr = *(const bf16x8*)((char*)Bs[P] + swz(n * 16 + l15, kbyte));      \
      acc[0][n] = __builtin_amdgcn_mfma_f32_16x16x32_bf16(af0, bfr, acc[0][n], 0, 0, 0); \
      acc[1][n] = __builtin_amdgcn_mfma_f32_16x16x32_bf16(af1, bfr, acc[1][n], 0, 0, 0); \
    }                                                                       \
  }

  int nt = Kd >> 6;
  GLOADA2(0, 0);
  LOADB2(0);
  GLOADA2(1, 64);
  WRITEB2(0);
  LOADB2(64);
  asm volatile("s_waitcnt vmcnt(0) lgkmcnt(0)" ::: "memory");
  __builtin_amdgcn_sched_barrier(0);
  __builtin_amdgcn_s_barrier();
  __builtin_amdgcn_sched_barrier(0);
  for (int t = 0; t < nt; ++t) {
    int p = t & 1;
    __builtin_amdgcn_s_setprio(1);
    MFMA2(p);
    __builtin_amdgcn_s_setprio(0);
    __builtin_amdgcn_sched_barrier(0);
    if (t + 2 < nt) GLOADA2(p, (t + 2) << 6);
    if (t + 1 < nt) WRITEB2(p ^ 1);
    if (t + 2 < nt) {
      LOADB2((t + 2) << 6);
      asm volatile("s_waitcnt vmcnt(8) lgkmcnt(0)" ::: "memory");  // drain A(t+1)
    } else {
      asm volatile("s_waitcnt vmcnt(0) lgkmcnt(0)" ::: "memory");
    }
    __builtin_amdgcn_sched_barrier(0);
    __builtin_amdgcn_s_barrier();
    __builtin_amdgcn_sched_barrier(0);
  }
#undef GLOADA2
#undef LOADB2
#undef WRITEB2
#undef MFMA2

  if (dstF) {
#pragma unroll
    for (int m = 0; m < 2; ++m)
#pragma unroll
      for (int n = 0; n < 4; ++n)
#pragma unroll
        for (int r = 0; r < 4; ++r) {
          int lrow = wr * 32 + m * 16 + lhi * 4 + r;
          int col = n0 + n * 16 + l15;
          dstF[(size_t)(m0 + lrow) * Hn + col] = acc[m][n][r];
        }
  } else {
#pragma unroll
    for (int m = 0; m < 2; ++m)
#pragma unroll
      for (int n = 0; n < 4; ++n)
#pragma unroll
        for (int r = 0; r < 4; ++r) {
          int lrow = wr * 32 + m * 16 + lhi * 4 + r;
          if (lrow >= mlim) continue;
          int col = n0 + n * 16 + l15;
          dstB[(size_t)(m0 + lrow) * Hn + col] = (__bf16)acc[m][n][r];
        }
  }
}

// ---------------- combine: out[t] = shared_out[t] + sum_k w_k * y[e_k, pos_k] ----------------
__global__ void combine_kernel(const int* __restrict__ ids, const float* __restrict__ tw,
                               const int* __restrict__ ppos, const __bf16* __restrict__ y,
                               float* __restrict__ out) {
  int t = blockIdx.x;
  int c0 = threadIdx.x * 8;
  float* orow = out + (size_t)t * Hn + c0;
  float4 a0 = *(const float4*)orow;
  float4 a1 = *(const float4*)(orow + 4);
#pragma unroll
  for (int k = 0; k < Kn; ++k) {
    int f = t * Kn + k;
    int p = ppos[f];
    if (p < 0) continue;
    int e = ids[f];
    float w = tw[f];
    bf16x8 bv = *(const bf16x8*)(y + ((size_t)e * Cn + p) * Hn + c0);
    a0.x += w * (float)bv[0]; a0.y += w * (float)bv[1];
    a0.z += w * (float)bv[2]; a0.w += w * (float)bv[3];
    a1.x += w * (float)bv[4]; a1.y += w * (float)bv[5];
    a1.z += w * (float)bv[6]; a1.w += w * (float)bv[7];
  }
  *(float4*)orow = a0;
  *(float4*)(orow + 4) = a1;
}

extern "C" void kernel_launch(void* const* d_in, const int* in_sizes, int n_in,
                              void* d_out, int out_size, void* d_ws, size_t ws_size,
                              hipStream_t stream) {
  (void)in_sizes; (void)n_in; (void)out_size; (void)ws_size;
  const float* x   = (const float*)d_in[0];
  const float* gw  = (const float*)d_in[1];
  const float* gb  = (const float*)d_in[2];
  const float* w13 = (const float*)d_in[3];
  const float* w2  = (const float*)d_in[4];
  const float* sgu = (const float*)d_in[5];
  const float* sdn = (const float*)d_in[6];
  float* out = (float*)d_out;

  char* ws = (char*)d_ws;
  size_t off = 0;
  int* ids   = (int*)(ws + off);   off += (size_t)Tn * Kn * 4;
  float* tw  = (float*)(ws + off); off += (size_t)Tn * Kn * 4;
  int* ppos  = (int*)(ws + off);   off += (size_t)Tn * Kn * 4;
  int* etok  = (int*)(ws + off);   off += (size_t)En * Cn * 4;
  int* ecnt  = (int*)(ws + off);   off += 256;
  __bf16* xbf  = (__bf16*)(ws + off); off += (size_t)Tn * Hn * 2;
  __bf16* hmid = (__bf16*)(ws + off); off += (size_t)En * Cn * In * 2;
  __bf16* smid = (__bf16*)(ws + off); off += (size_t)Tn * Sn * 2;
  __bf16* y    = (__bf16*)(ws + off); off += (size_t)En * Cn * Hn * 2;

  router_kernel<<<Tn, 64, 0, stream>>>(x, gw, gb, ids, tw, xbf);
  dispatch_kernel<<<En, 256, 0, stream>>>(ids, etok, ppos, ecnt);

  // gemm1: 256 shared + 2048 expert blocks (XCD-decomposed)
  gemm1_fused<<<dim3(256 + 2048), 512, 0, stream>>>(xbf, etok, ecnt, w13, sgu, hmid, smid);
  // gemm2: 256 shared (-> out fp32) + 4096 expert (-> y bf16), no atomics
  gemm2_fused<<<dim3(256 + 4096), 256, 0, stream>>>(hmid, smid, w2, sdn, ecnt, y, out);
  // combine: weighted gather of y + shared out
  combine_kernel<<<Tn, 256, 0, stream>>>(ids, tw, ppos, y, out);
}